// Round 14
// baseline (515.559 us; speedup 1.0000x reference)
//
#include <hip/hip_runtime.h>
#include <hip/hip_bf16.h>
#include <cstddef>

#define NC 16
#define HID 128
#define IMH 256
#define IMW 256
#define NB 32
#define TILE 16
#define HR 18
#define XS 20
#define WROW 36
#define NPIX (HR*HR)
#define NTILES 21
#define FSTR 40      // fused-fallback feat stride
#define K1T 256      // k1 threads
#define K1FS 32      // k1 feat row stride (u16)

typedef __attribute__((ext_vector_type(8))) short bf16x8;
typedef __attribute__((ext_vector_type(4))) float f32x4;
typedef __attribute__((ext_vector_type(4))) unsigned u32x4;

union UB { u32x4 u; bf16x8 v; };

static __device__ __forceinline__ unsigned short f2bf(float x) {
    union { __hip_bfloat16 b; unsigned short u; } v;
    v.b = __float2bfloat16(x);
    return v.u;
}
static __device__ __forceinline__ float bf2f(unsigned short u) {
    union { __hip_bfloat16 b; unsigned short u; } v;
    v.u = u;
    return __bfloat162float(v.b);
}
static __device__ __forceinline__ unsigned pack2(float a, float b) {
    return (unsigned)f2bf(a) | ((unsigned)f2bf(b) << 16);
}

// ---------------- weight prep ----------------
__global__ void prep_weights(const float* __restrict__ w1,
                             const float* __restrict__ b1,
                             const float* __restrict__ w2,
                             float* __restrict__ wpack,
                             unsigned short* __restrict__ w1pb,
                             unsigned short* __restrict__ w2b,
                             float* __restrict__ w2row3) {
    int j = threadIdx.x;
    if (j >= HID) return;
    const int starts[18] = {0,3,6,9,12,15,16,18,21,24,27,30,32,33,36,39,42,45};
    const int lens[18]   = {3,3,3,3,3,1,2,3,3,3,3,2,1,3,3,3,3,3};
    float* row = wpack + j * WROW;
    row[0] = b1[j];
    float we[18];
    #pragma unroll
    for (int f = 0; f < 18; ++f) {
        float s = 0.f;
        for (int k = 0; k < lens[f]; ++k) s += w1[j*48 + starts[f] + k];
        we[f] = s;
        row[1+f] = s;
    }
    #pragma unroll
    for (int c = 0; c < NC; ++c) row[19+c] = w2[c*HID + j];
    row[35] = 0.f;
    #pragma unroll
    for (int g = 0; g < 4; ++g)
        #pragma unroll
        for (int r = 0; r < 8; ++r) {
            int k = g*8 + r;
            w1pb[(j*4 + g)*8 + r] = f2bf(k < 18 ? we[k] : 0.f);
        }
    #pragma unroll
    for (int c = 0; c < NC; ++c) w2b[c*HID + j] = f2bf(w2[c*HID + j]);
    w2row3[j] = w2[3*HID + j];
}

// ======== shared front-end: stage X to LDS + fp32 features (macro'd for probes) ====
#define K1_FRONTEND(SXARR, FARR)                                                  \
    if (t < 160) {                                                                \
        const int ch = t / 10, r = t - ch*10;                                     \
        const int sgy = blockIdx.y*8 + r - 1;                                     \
        const bool yok = (sgy >= 0 && sgy < IMH);                                 \
        const float* src = Xb + (size_t)ch*65536 + (size_t)(yok ? sgy : 0)*IMW;   \
        float buf[40];                                                            \
        const float4 z = {0.f,0.f,0.f,0.f};                                       \
        _Pragma("unroll")                                                         \
        for (int j = 0; j < 10; ++j) {                                            \
            const int col = x0 - 4 + 4*j;                                         \
            const bool ok = yok && col >= 0 && col <= 252;                        \
            *(float4*)&buf[4*j] = ok ? *(const float4*)(src + col) : z;           \
        }                                                                         \
        _Pragma("unroll")                                                         \
        for (int k = 0; k < 9; ++k) {                                             \
            float4 v = { buf[4*k+2], buf[4*k+3], buf[4*k+4], buf[4*k+5] };        \
            *(float4*)&SXARR[ch][r][4*k] = v;                                     \
        }                                                                         \
    }                                                                             \
    __syncthreads();                                                              \
    const int sr = ly + 1, sc = lx + 2;                                           \
    float FARR[18];                                                               \
    _Pragma("unroll")                                                             \
    for (int c = 0; c < 6; ++c) FARR[c] = SXARR[c][sr][sc];                       \
    _Pragma("unroll")                                                             \
    for (int i = 0; i < 5; ++i) {                                                 \
        const int ch = 5 + i;                                                     \
        float a  = SXARR[ch][sr-1][sc+1] - SXARR[ch][sr-1][sc-1];                 \
        float bb = SXARR[ch][sr  ][sc+1] - SXARR[ch][sr  ][sc-1];                 \
        float cc = SXARR[ch][sr+1][sc+1] - SXARR[ch][sr+1][sc-1];                 \
        FARR[6+i] = (a + 2.f*bb + cc) * 0.125f;                                   \
    }                                                                             \
    {                                                                             \
        float tl = SXARR[10][sr-1][sc-1], tc = SXARR[10][sr-1][sc], tr = SXARR[10][sr-1][sc+1]; \
        float ml = SXARR[10][sr][sc-1],                             mr = SXARR[10][sr][sc+1];   \
        float bl = SXARR[10][sr+1][sc-1], bc = SXARR[10][sr+1][sc], br = SXARR[10][sr+1][sc+1]; \
        FARR[11] = ((tr-tl) + 2.f*(mr-ml) + (br-bl)) * 0.125f;                    \
        FARR[12] = ((bl + 2.f*bc + br) - (tl + 2.f*tc + tr)) * 0.125f;            \
    }                                                                             \
    _Pragma("unroll")                                                             \
    for (int i = 0; i < 5; ++i) {                                                 \
        const int ch = 11 + i;                                                    \
        float tp = SXARR[ch][sr-1][sc-1] + 2.f*SXARR[ch][sr-1][sc] + SXARR[ch][sr-1][sc+1]; \
        float bt = SXARR[ch][sr+1][sc-1] + 2.f*SXARR[ch][sr+1][sc] + SXARR[ch][sr+1][sc+1]; \
        FARR[13+i] = (bt - tp) * 0.125f;                                          \
    }

#define K1_PACK(FARR)                                                             \
    {                                                                             \
        unsigned w[9];                                                            \
        _Pragma("unroll")                                                         \
        for (int q = 0; q < 9; ++q) w[q] = pack2(FARR[2*q], FARR[2*q+1]);         \
        u32x4 v0 = { w[0], w[1], w[2], w[3] };                                    \
        u32x4 v1 = { w[4], w[5], w[6], w[7] };                                    \
        u32x4 v2 = { w[8], 0u, 0u, 0u };                                          \
        u32x4 z4 = { 0u, 0u, 0u, 0u };                                            \
        *(u32x4*)&feat[t][0]  = v0;                                               \
        *(u32x4*)&feat[t][8]  = v1;                                               \
        *(u32x4*)&feat[t][16] = v2;                                               \
        *(u32x4*)&feat[t][24] = z4;                                               \
    }

#define K1_TILE_BODY(LID)                                                        \
    do {                                                                         \
        const int row = wave*64 + (LID);                                         \
        bf16x8 fb = *(const bf16x8*)&feat[row][g*8];                             \
        f32x4 dacc = { 0.f, 0.f, 0.f, 0.f };                                     \
        float part = 0.f;                                                        \
        _Pragma("unroll")                                                        \
        for (int kc = 0; kc < 4; ++kc) {                                         \
            const int nt0 = 2*kc, nt1 = 2*kc + 1;                                \
            float4 bv0 = *(const float4*)(b1g + nt0*16 + g*4);                   \
            float4 bv1 = *(const float4*)(b1g + nt1*16 + g*4);                   \
            f32x4 ci0 = { bv0.x, bv0.y, bv0.z, bv0.w };                          \
            f32x4 ci1 = { bv1.x, bv1.y, bv1.z, bv1.w };                          \
            f32x4 acc0 = __builtin_amdgcn_mfma_f32_16x16x32_bf16(w1f[nt0], fb, ci0, 0, 0, 0); \
            f32x4 acc1 = __builtin_amdgcn_mfma_f32_16x16x32_bf16(w1f[nt1], fb, ci1, 0, 0, 0); \
            float4 wv0 = *(const float4*)(w2row3 + nt0*16 + g*4);                \
            float4 wv1 = *(const float4*)(w2row3 + nt1*16 + g*4);                \
            float h00 = fmaxf(acc0[0], 0.f), h01 = fmaxf(acc0[1], 0.f);          \
            float h02 = fmaxf(acc0[2], 0.f), h03 = fmaxf(acc0[3], 0.f);          \
            float h10 = fmaxf(acc1[0], 0.f), h11 = fmaxf(acc1[1], 0.f);          \
            float h12 = fmaxf(acc1[2], 0.f), h13 = fmaxf(acc1[3], 0.f);          \
            part = fmaf(wv0.x, h00, part); part = fmaf(wv0.y, h01, part);        \
            part = fmaf(wv0.z, h02, part); part = fmaf(wv0.w, h03, part);        \
            part = fmaf(wv1.x, h10, part); part = fmaf(wv1.y, h11, part);        \
            part = fmaf(wv1.z, h12, part); part = fmaf(wv1.w, h13, part);        \
            unsigned p00 = pack2(h00, h01), p01 = pack2(h02, h03);               \
            unsigned p10 = pack2(h10, h11), p11 = pack2(h12, h13);               \
            int a0s = __shfl((int)p00, srcA, 64);                                \
            int b0s = __shfl((int)p10, srcA, 64);                                \
            int a1s = __shfl((int)p01, srcA, 64);                                \
            int b1s = __shfl((int)p11, srcA, 64);                                \
            int a2s = __shfl((int)p00, srcB, 64);                                \
            int b2s = __shfl((int)p10, srcB, 64);                                \
            int a3s = __shfl((int)p01, srcB, 64);                                \
            int b3s = __shfl((int)p11, srcB, 64);                                \
            UB bu;                                                               \
            bu.u[0] = (unsigned)(hi ? b0s : a0s);                                \
            bu.u[1] = (unsigned)(hi ? b1s : a1s);                                \
            bu.u[2] = (unsigned)(hi ? b2s : a2s);                                \
            bu.u[3] = (unsigned)(hi ? b3s : a3s);                                \
            dacc = __builtin_amdgcn_mfma_f32_16x16x32_bf16(w2fA[kc], bu.v, dacc, 0, 0, 0); \
        }                                                                        \
        part += __shfl_xor(part, 16, 64);                                        \
        part += __shfl_xor(part, 32, 64);                                        \
        if (g == 0) *(float*)&feat[row][20] = part;                              \
        *(unsigned*)&feat[row][g*4]     = pack2(dacc[0], dacc[1]);               \
        *(unsigned*)&feat[row][g*4 + 2] = pack2(dacc[2], dacc[3]);               \
    } while (0)

// ================= PROBE A: front-end only (staging + features + pack) ============
__global__ __launch_bounds__(K1T, 4)
void k1_p_feat(const float* __restrict__ X,
               const float* __restrict__ rand_u,
               float* __restrict__ scratch) {
    __shared__ __align__(16) float sX[NC][10][36];
    __shared__ __align__(16) unsigned short feat[K1T][K1FS];

    const int t  = threadIdx.x;
    const int lx = t & 31, ly = t >> 5;
    const int x0 = blockIdx.x*32;
    const int gx = x0 + lx;
    const int gy = blockIdx.y*8 + ly;
    const int b  = blockIdx.z;
    const int off = gy*IMW + gx;
    const float* Xb = X + (size_t)b * NC * IMH * IMW;
    const float ruv = rand_u[(size_t)b*65536 + off];

    K1_FRONTEND(sX, f)
    K1_PACK(f)
    asm volatile("s_waitcnt lgkmcnt(0)" ::: "memory");

    float v = ruv;
    #pragma unroll
    for (int k = 0; k < 18; ++k) v += f[k];
    scratch[(size_t)b*65536 + off] = v;
}

// ================= PROBE B: front-end + compaction + MFMA tiles ===================
__global__ __launch_bounds__(K1T, 4)
void k1_p_mlp(const float* __restrict__ X,
              const float* __restrict__ rand_u,
              const float* __restrict__ b1g,
              const unsigned short* __restrict__ w1pb,
              const unsigned short* __restrict__ w2b,
              const float* __restrict__ w2row3,
              float* __restrict__ scratch) {
    __shared__ __align__(16) float sX[NC][10][36];
    __shared__ __align__(16) unsigned short feat[K1T][K1FS];
    __shared__ unsigned short sList[4][64];

    const int t    = threadIdx.x;
    const int lx   = t & 31, ly = t >> 5;
    const int x0   = blockIdx.x*32;
    const int gx   = x0 + lx;
    const int gy   = blockIdx.y*8 + ly;
    const int b    = blockIdx.z;
    const int lane = t & 63;
    const int c15  = lane & 15;
    const int g    = lane >> 4;
    const int wave = t >> 6;
    const int off  = gy*IMW + gx;
    const float* Xb = X + (size_t)b * NC * IMH * IMW;
    const float ruv = rand_u[(size_t)b*65536 + off];

    K1_FRONTEND(sX, f)
    asm volatile("" ::: "memory");
    bf16x8 w1f[8];
    #pragma unroll
    for (int nt = 0; nt < 8; ++nt)
        w1f[nt] = *(const bf16x8*)(w1pb + ((nt*16 + c15)*4 + g)*8);
    bf16x8 w2fA[4];
    #pragma unroll
    for (int kc = 0; kc < 4; ++kc)
        w2fA[kc] = *(const bf16x8*)(w2b + c15*128 + kc*32 + g*8);
    K1_PACK(f)

    const bool active = (ruv < 0.5f);
    const unsigned long long wm = __ballot(active);
    const int count = __popcll(wm);
    const int ntiles = (count + 15) >> 4;
    if (active) {
        const int pf = __popcll(wm & ((1ull << lane) - 1ull));
        sList[wave][pf] = (unsigned short)lane;
    }
    asm volatile("s_waitcnt lgkmcnt(0)" ::: "memory");
    __builtin_amdgcn_sched_barrier(0);

    const int safe = (count < 64) ? ((int)__ffsll((long long)(~wm)) - 1) : 0;
    int lid0 = safe, lid1 = safe, lid2 = safe, lid3 = safe;
    if (0*16 + c15 < count) lid0 = sList[wave][0*16 + c15];
    if (1*16 + c15 < count) lid1 = sList[wave][1*16 + c15];
    if (2*16 + c15 < count) lid2 = sList[wave][2*16 + c15];
    if (3*16 + c15 < count) lid3 = sList[wave][3*16 + c15];

    const int srcA = ((( g<<1     ) & 3) << 4) + c15;
    const int srcB = ((((g<<1) + 1) & 3) << 4) + c15;
    const bool hi  = (g >= 2);

    if (ntiles > 0) K1_TILE_BODY(lid0);
    if (ntiles > 1) K1_TILE_BODY(lid1);
    if (ntiles > 2) K1_TILE_BODY(lid2);
    if (ntiles > 3) K1_TILE_BODY(lid3);

    asm volatile("s_waitcnt lgkmcnt(0)" ::: "memory");
    __builtin_amdgcn_sched_barrier(0);

    float dx3 = *(const float*)&feat[t][20];
    u32x4 da = *(const u32x4*)&feat[t][0];
    scratch[(size_t)b*65536 + off] = dx3 + (float)(int)da.x;
}

// ================= K1: real (identical to R13) =================
__global__ __launch_bounds__(K1T, 4)
void k1_dx(const float* __restrict__ X,
           const float* __restrict__ rand_u,
           const float* __restrict__ b1g,
           const float* __restrict__ wpack,
           const unsigned short* __restrict__ w1pb,
           const unsigned short* __restrict__ w2b,
           const float* __restrict__ w2row3,
           float* __restrict__ xn3buf,
           float* __restrict__ out) {
    __shared__ __align__(16) float sX[NC][10][36];
    __shared__ __align__(16) unsigned short feat[K1T][K1FS];
    __shared__ unsigned short sList[4][64];

    const int t    = threadIdx.x;
    const int lx   = t & 31, ly = t >> 5;
    const int x0   = blockIdx.x*32;
    const int gx   = x0 + lx;
    const int gy   = blockIdx.y*8 + ly;
    const int b    = blockIdx.z;
    const int lane = t & 63;
    const int c15  = lane & 15;
    const int g    = lane >> 4;
    const int wave = t >> 6;
    const int off  = gy*IMW + gx;
    const float* Xb = X + (size_t)b * NC * IMH * IMW;
    const float ruv = rand_u[(size_t)b*65536 + off];

    K1_FRONTEND(sX, f)
    asm volatile("" ::: "memory");
    bf16x8 w1f[8];
    #pragma unroll
    for (int nt = 0; nt < 8; ++nt)
        w1f[nt] = *(const bf16x8*)(w1pb + ((nt*16 + c15)*4 + g)*8);
    bf16x8 w2fA[4];
    #pragma unroll
    for (int kc = 0; kc < 4; ++kc)
        w2fA[kc] = *(const bf16x8*)(w2b + c15*128 + kc*32 + g*8);
    K1_PACK(f)

    const bool active = (ruv < 0.5f);
    const unsigned long long wm = __ballot(active);
    const int count = __popcll(wm);
    const int ntiles = (count + 15) >> 4;
    if (active) {
        const int pf = __popcll(wm & ((1ull << lane) - 1ull));
        sList[wave][pf] = (unsigned short)lane;
    }
    asm volatile("s_waitcnt lgkmcnt(0)" ::: "memory");
    __builtin_amdgcn_sched_barrier(0);

    const int safe = (count < 64) ? ((int)__ffsll((long long)(~wm)) - 1) : 0;
    int lid0 = safe, lid1 = safe, lid2 = safe, lid3 = safe;
    if (0*16 + c15 < count) lid0 = sList[wave][0*16 + c15];
    if (1*16 + c15 < count) lid1 = sList[wave][1*16 + c15];
    if (2*16 + c15 < count) lid2 = sList[wave][2*16 + c15];
    if (3*16 + c15 < count) lid3 = sList[wave][3*16 + c15];

    const int srcA = ((( g<<1     ) & 3) << 4) + c15;
    const int srcB = ((((g<<1) + 1) & 3) << 4) + c15;
    const bool hi  = (g >= 2);

    if (ntiles > 0) K1_TILE_BODY(lid0);
    if (ntiles > 1) K1_TILE_BODY(lid1);
    if (ntiles > 2) K1_TILE_BODY(lid2);
    if (ntiles > 3) K1_TILE_BODY(lid3);

    asm volatile("s_waitcnt lgkmcnt(0)" ::: "memory");
    __builtin_amdgcn_sched_barrier(0);

    const float X3 = sX[3][sr][sc];
    float xn3 = X3;
    if (active) {
        float dx3 = *(const float*)&feat[t][20];
        xn3 = dx3 + X3;
    }

    // WAVE-COOPERATIVE exact fp32 fallback near the alpha threshold (rare).
    {
        const bool need = active && (fabsf(xn3 - 0.1f) < 1e-3f);
        unsigned long long nm = __ballot(need);
        if (nm != 0ull) {
            const int j0 = lane*2, j1 = lane*2 + 1;
            while (nm != 0ull) {
                const int src = (int)__ffsll((long long)nm) - 1;
                nm &= nm - 1ull;
                const int off_e = __shfl(off, src, 64);
                const int gx_e = off_e & 255, gy_e = off_e >> 8;
                const bool yle = gy_e > 0, yhe = gy_e < IMH-1;
                const bool xle = gx_e > 0, xhe = gx_e < IMW-1;
                float fv = 0.f;
                if (lane < 6) {
                    fv = Xb[lane*65536 + off_e];
                } else if (lane < 12) {
                    const float* P = Xb + (lane-1)*65536 + off_e;
                    float tl = (yle&&xle) ? P[-257] : 0.f, tr = (yle&&xhe) ? P[-255] : 0.f;
                    float ml = xle ? P[-1] : 0.f,          mr = xhe ? P[1] : 0.f;
                    float bl = (yhe&&xle) ? P[255] : 0.f,  br = (yhe&&xhe) ? P[257] : 0.f;
                    fv = ((tr-tl) + 2.f*(mr-ml) + (br-bl)) * 0.125f;
                } else if (lane < 18) {
                    const float* P = Xb + (lane-2)*65536 + off_e;
                    float tl = (yle&&xle) ? P[-257] : 0.f, tc = yle ? P[-256] : 0.f, tr = (yle&&xhe) ? P[-255] : 0.f;
                    float bl = (yhe&&xle) ? P[255]  : 0.f, bc = yhe ? P[256]  : 0.f, br = (yhe&&xhe) ? P[257]  : 0.f;
                    fv = ((bl + 2.f*bc + br) - (tl + 2.f*tc + tr)) * 0.125f;
                }
                float fe[18];
                #pragma unroll
                for (int k = 0; k < 18; ++k) fe[k] = __shfl(fv, k, 64);
                const float* r0 = wpack + j0*WROW;
                const float* r1 = wpack + j1*WROW;
                float h0 = r0[0], h1 = r1[0];
                #pragma unroll
                for (int k = 0; k < 18; ++k) {
                    h0 = fmaf(r0[1+k], fe[k], h0);
                    h1 = fmaf(r1[1+k], fe[k], h1);
                }
                h0 = fmaxf(h0, 0.f); h1 = fmaxf(h1, 0.f);
                float d = fmaf(r0[22], h0, r1[22]*h1);
                #pragma unroll
                for (int o = 1; o < 64; o <<= 1) d += __shfl_xor(d, o, 64);
                if (lane == src) xn3 = __shfl(X3, src, 64) + d;
            }
        }
    }

    xn3buf[(size_t)b*65536 + off] = xn3;
    u32x4 da = *(const u32x4*)&feat[t][0];
    u32x4 db = *(const u32x4*)&feat[t][8];
    float* ob = out + (size_t)b*NC*65536 + off;
    unsigned dw[8] = { da.x, da.y, da.z, da.w, db.x, db.y, db.z, db.w };
    #pragma unroll
    for (int c = 0; c < NC; ++c) {
        unsigned short u = (c & 1) ? (unsigned short)(dw[c>>1] >> 16)
                                   : (unsigned short)(dw[c>>1] & 0xffff);
        const float xc = sX[c][sr][sc];
        float val = (c == 3) ? xn3 : (active ? (bf2f(u) + xc) : xc);
        ob[c*65536] = val;
    }
}

// ================= K2: live mask, out *= live =================
__global__ __launch_bounds__(512, 4)
void k2_mask(const float* __restrict__ X,
             const float* __restrict__ xn3buf,
             float* out) {
    __shared__ float sPre[HR][34];
    __shared__ float sPost[HR][34];

    const int t  = threadIdx.x;
    const int x0 = blockIdx.x*32, y0 = blockIdx.y*16;
    const int b  = blockIdx.z;

    const float* X3p = X + (size_t)b*NC*65536 + 3*65536;
    const float* Pp  = xn3buf + (size_t)b*65536;
    for (int e = t; e < HR*34; e += 512) {
        int row = e / 34, col = e - row*34;
        int gy = y0 + row - 1, gx = x0 + col - 1;
        bool ok = (gy >= 0 && gy < IMH && gx >= 0 && gx < IMW);
        int idx = (gy & 255)*IMW + (gx & 255);
        sPre[row][col]  = ok ? X3p[idx] : 0.f;
        sPost[row][col] = ok ? Pp[idx]  : 0.f;
    }
    __syncthreads();

    const int lx = t & 31, ly = t >> 5;
    float mpre = -1.f, mpost = -1.f;
    #pragma unroll
    for (int dy = 0; dy < 3; ++dy)
        #pragma unroll
        for (int dxx = 0; dxx < 3; ++dxx) {
            mpre  = fmaxf(mpre,  sPre[ly+dy][lx+dxx]);
            mpost = fmaxf(mpost, sPost[ly+dy][lx+dxx]);
        }
    const float live = (mpre > 0.1f && mpost > 0.1f) ? 1.f : 0.f;
    const int off = (y0+ly)*IMW + (x0+lx);
    float* ob = out + (size_t)b*NC*65536 + off;
    #pragma unroll
    for (int c = 0; c < NC; ++c) {
        float v = ob[c*65536];
        ob[c*65536] = v * live;
    }
}

// ================= fallback fused kernel (ws too small; same as R7) ===============
__global__ __launch_bounds__(512, 3)
void nca_fused(const float* __restrict__ X,
               const float* __restrict__ rand_u,
               const float* __restrict__ b1g,
               const float* __restrict__ wpack,
               const unsigned short* __restrict__ w1pb,
               const unsigned short* __restrict__ w2b,
               const float* __restrict__ w2row3,
               float* __restrict__ out) {
    __shared__ __align__(16) float sX[NC][XS][XS];
    __shared__ __align__(16) unsigned short feat[336][FSTR];
    __shared__ __align__(16) float sB1[HID];
    __shared__ __align__(16) float sW23[HID];

    const int t    = threadIdx.x;
    const int x0   = blockIdx.x * TILE;
    const int y0   = blockIdx.y * TILE;
    const int b    = blockIdx.z;
    const int lane = t & 63;
    const int c15  = lane & 15;
    const int g    = lane >> 4;
    const int wave = t >> 6;

    const float* Xb = X + (size_t)b * NC * IMH * IMW;

    if (t < HID) { sB1[t] = b1g[t]; sW23[t] = w2row3[t]; }

    if (t < NC*XS) {
        int ch = t / XS, row = t % XS;
        int gy = y0 + row - 2;
        bool yok = (gy >= 0 && gy < IMH);
        const float* src = Xb + (size_t)ch*IMH*IMW + (size_t)(yok ? gy : 0)*IMW;
        float4 z = {0.f,0.f,0.f,0.f};
        float buf[24];
        *(float4*)&buf[0]  = (yok && x0 > 0)   ? *(const float4*)(src + x0 - 4)  : z;
        *(float4*)&buf[4]  = yok               ? *(const float4*)(src + x0)      : z;
        *(float4*)&buf[8]  = yok               ? *(const float4*)(src + x0 + 4)  : z;
        *(float4*)&buf[12] = yok               ? *(const float4*)(src + x0 + 8)  : z;
        *(float4*)&buf[16] = yok               ? *(const float4*)(src + x0 + 12) : z;
        *(float4*)&buf[20] = (yok && x0 < 240) ? *(const float4*)(src + x0 + 16) : z;
        #pragma unroll
        for (int k = 0; k < 5; ++k) {
            float4 v = { buf[4*k+2], buf[4*k+3], buf[4*k+4], buf[4*k+5] };
            *(float4*)&sX[ch][row][4*k] = v;
        }
    }
    float m_reg = 0.f;
    if (t < NPIX) {
        int py = t / HR, px = t - py*HR;
        int gy = y0 + py - 1, gx = x0 + px - 1;
        if (gy >= 0 && gy < IMH && gx >= 0 && gx < IMW)
            m_reg = (rand_u[((size_t)b << 16) + (gy << 8) + gx] < 0.5f) ? 1.f : 0.f;
    }
    __syncthreads();

    if (t < NPIX) {
        const int py = t / HR, px = t - py*HR;
        const int cy = py + 1, cx = px + 1;
        float f[18];
        #pragma unroll
        for (int c = 0; c < 6; ++c) f[c] = sX[c][cy][cx];
        #pragma unroll
        for (int i = 0; i < 6; ++i) {
            const int ch = 5 + i;
            float a  = sX[ch][cy-1][cx+1] - sX[ch][cy-1][cx-1];
            float bb = sX[ch][cy  ][cx+1] - sX[ch][cy  ][cx-1];
            float cc = sX[ch][cy+1][cx+1] - sX[ch][cy+1][cx-1];
            f[6+i] = (a + 2.f*bb + cc) * 0.125f;
        }
        #pragma unroll
        for (int i = 0; i < 6; ++i) {
            const int ch = 10 + i;
            float tp = sX[ch][cy-1][cx-1] + 2.f*sX[ch][cy-1][cx] + sX[ch][cy-1][cx+1];
            float bt = sX[ch][cy+1][cx-1] + 2.f*sX[ch][cy+1][cx] + sX[ch][cy+1][cx+1];
            f[12+i] = (bt - tp) * 0.125f;
        }
        unsigned w[9];
        #pragma unroll
        for (int q = 0; q < 9; ++q) w[q] = pack2(f[2*q], f[2*q+1]);
        u32x4 v0 = { w[0], w[1], w[2], w[3] };
        u32x4 v1 = { w[4], w[5], w[6], w[7] };
        u32x4 v2 = { w[8], 0u, 0u, 0u };
        u32x4 z4 = { 0u, 0u, 0u, 0u };
        *(u32x4*)&feat[t][0]  = v0;
        *(u32x4*)&feat[t][8]  = v1;
        *(u32x4*)&feat[t][16] = v2;
        *(u32x4*)&feat[t][24] = z4;
    } else if (t < 336) {
        u32x4 z4 = { 0u, 0u, 0u, 0u };
        *(u32x4*)&feat[t][0]  = z4;
        *(u32x4*)&feat[t][8]  = z4;
        *(u32x4*)&feat[t][16] = z4;
        *(u32x4*)&feat[t][24] = z4;
    }
    __syncthreads();

    const int srcA = ((( g<<1     ) & 3) << 4) + c15;
    const int srcB = ((((g<<1) + 1) & 3) << 4) + c15;
    const bool hi  = (g >= 2);
    #pragma unroll 1
    for (int tile = wave; tile < NTILES; tile += 8) {
        const unsigned short* w1p_ = w1pb;
        const unsigned short* w2p_ = w2b;
        asm volatile("" : "+v"(w1p_), "+v"(w2p_));

        bf16x8 fb = *(const bf16x8*)&feat[tile*16 + c15][g*8];
        f32x4 dacc = { 0.f, 0.f, 0.f, 0.f };
        float part = 0.f;
        #pragma unroll
        for (int kc = 0; kc < 4; ++kc) {
            const int nt0 = 2*kc, nt1 = 2*kc + 1;
            bf16x8 a0 = *(const bf16x8*)(w1p_ + ((nt0*16 + c15)*4 + g)*8);
            bf16x8 a1 = *(const bf16x8*)(w1p_ + ((nt1*16 + c15)*4 + g)*8);
            float4 bv0 = *(const float4*)&sB1[nt0*16 + g*4];
            float4 bv1 = *(const float4*)&sB1[nt1*16 + g*4];
            f32x4 ci0 = { bv0.x, bv0.y, bv0.z, bv0.w };
            f32x4 ci1 = { bv1.x, bv1.y, bv1.z, bv1.w };
            f32x4 acc0 = __builtin_amdgcn_mfma_f32_16x16x32_bf16(a0, fb, ci0, 0, 0, 0);
            f32x4 acc1 = __builtin_amdgcn_mfma_f32_16x16x32_bf16(a1, fb, ci1, 0, 0, 0);
            float4 wv0 = *(const float4*)&sW23[nt0*16 + g*4];
            float4 wv1 = *(const float4*)&sW23[nt1*16 + g*4];
            float h00 = fmaxf(acc0[0], 0.f), h01 = fmaxf(acc0[1], 0.f);
            float h02 = fmaxf(acc0[2], 0.f), h03 = fmaxf(acc0[3], 0.f);
            float h10 = fmaxf(acc1[0], 0.f), h11 = fmaxf(acc1[1], 0.f);
            float h12 = fmaxf(acc1[2], 0.f), h13 = fmaxf(acc1[3], 0.f);
            part = fmaf(wv0.x, h00, part); part = fmaf(wv0.y, h01, part);
            part = fmaf(wv0.z, h02, part); part = fmaf(wv0.w, h03, part);
            part = fmaf(wv1.x, h10, part); part = fmaf(wv1.y, h11, part);
            part = fmaf(wv1.z, h12, part); part = fmaf(wv1.w, h13, part);
            unsigned p00 = pack2(h00, h01), p01 = pack2(h02, h03);
            unsigned p10 = pack2(h10, h11), p11 = pack2(h12, h13);
            int a0s = __shfl((int)p00, srcA, 64);
            int b0s = __shfl((int)p10, srcA, 64);
            int a1s = __shfl((int)p01, srcA, 64);
            int b1s = __shfl((int)p11, srcA, 64);
            int a2s = __shfl((int)p00, srcB, 64);
            int b2s = __shfl((int)p10, srcB, 64);
            int a3s = __shfl((int)p01, srcB, 64);
            int b3s = __shfl((int)p11, srcB, 64);
            UB bu;
            bu.u[0] = (unsigned)(hi ? b0s : a0s);
            bu.u[1] = (unsigned)(hi ? b1s : a1s);
            bu.u[2] = (unsigned)(hi ? b2s : a2s);
            bu.u[3] = (unsigned)(hi ? b3s : a3s);
            bf16x8 w2a = *(const bf16x8*)(w2p_ + c15*128 + kc*32 + g*8);
            dacc = __builtin_amdgcn_mfma_f32_16x16x32_bf16(w2a, bu.v, dacc, 0, 0, 0);
        }
        part += __shfl_xor(part, 16, 64);
        part += __shfl_xor(part, 32, 64);
        if (g == 0) *(float*)&feat[tile*16 + c15][34] = part;
        *(unsigned*)&feat[tile*16 + c15][g*4]     = pack2(dacc[0], dacc[1]);
        *(unsigned*)&feat[tile*16 + c15][g*4 + 2] = pack2(dacc[2], dacc[3]);
    }
    __syncthreads();

    if (t < NPIX) {
        const int py = t / HR, px = t - py*HR;
        const int cy = py + 1, cx = px + 1;
        float dx3 = *(const float*)&feat[t][34];
        float X3  = sX[3][cy][cx];
        float xn3 = fmaf(dx3, m_reg, X3);
        if (m_reg != 0.f && fabsf(xn3 - 0.1f) < 1e-3f) {
            float f[18];
            #pragma unroll
            for (int c = 0; c < 6; ++c) f[c] = sX[c][cy][cx];
            #pragma unroll
            for (int i = 0; i < 6; ++i) {
                const int ch = 5 + i;
                f[6+i] = ((sX[ch][cy-1][cx+1] - sX[ch][cy-1][cx-1])
                        + 2.f*(sX[ch][cy][cx+1] - sX[ch][cy][cx-1])
                        + (sX[ch][cy+1][cx+1] - sX[ch][cy+1][cx-1])) * 0.125f;
            }
            #pragma unroll
            for (int i = 0; i < 6; ++i) {
                const int ch = 10 + i;
                f[12+i] = ((sX[ch][cy+1][cx-1] + 2.f*sX[ch][cy+1][cx] + sX[ch][cy+1][cx+1])
                         - (sX[ch][cy-1][cx-1] + 2.f*sX[ch][cy-1][cx] + sX[ch][cy-1][cx+1])) * 0.125f;
            }
            float d3 = 0.f;
            for (int j = 0; j < HID; ++j) {
                const float* row = wpack + j*WROW;
                float hj = row[0];
                #pragma unroll
                for (int k = 0; k < 18; ++k) hj = fmaf(row[1+k], f[k], hj);
                hj = fmaxf(hj, 0.f);
                d3 = fmaf(row[22], hj, d3);
            }
            xn3 = X3 + d3;
        }
        *(float*)&feat[t][32] = xn3;
    }
    __syncthreads();

    if (t < NPIX) {
        const int py = t / HR, px = t - py*HR;
        if (py >= 1 && py <= TILE && px >= 1 && px <= TILE) {
            float mpre = -1.f, mpost = -1.f;
            #pragma unroll
            for (int dy = 0; dy < 3; ++dy)
                #pragma unroll
                for (int dxx = 0; dxx < 3; ++dxx) {
                    mpre  = fmaxf(mpre,  sX[3][py+dy][px+dxx]);
                    mpost = fmaxf(mpost, *(const float*)&feat[(py-1+dy)*HR + (px-1+dxx)][32]);
                }
            const float live = (mpre > 0.1f && mpost > 0.1f) ? 1.f : 0.f;
            const int gy = y0 + py - 1, gx = x0 + px - 1;
            float* ob = out + ((size_t)b*NC)*IMH*IMW + (size_t)gy*IMW + gx;
            u32x4 da = *(const u32x4*)&feat[t][0];
            u32x4 db = *(const u32x4*)&feat[t][8];
            float xn3 = *(const float*)&feat[t][32];
            unsigned dw[8] = { da.x, da.y, da.z, da.w, db.x, db.y, db.z, db.w };
            #pragma unroll
            for (int c = 0; c < NC; ++c) {
                unsigned short u = (c & 1) ? (unsigned short)(dw[c>>1] >> 16)
                                           : (unsigned short)(dw[c>>1] & 0xffff);
                float val = (c == 3) ? xn3
                                     : fmaf(bf2f(u), m_reg, sX[c][py+1][px+1]);
                ob[(size_t)c*IMH*IMW] = val * live;
            }
        }
    }
}

extern "C" void kernel_launch(void* const* d_in, const int* in_sizes, int n_in,
                              void* d_out, int out_size, void* d_ws, size_t ws_size,
                              hipStream_t stream) {
    const float* X  = (const float*)d_in[0];
    const float* w1 = (const float*)d_in[1];
    const float* b1 = (const float*)d_in[2];
    const float* w2 = (const float*)d_in[3];
    const float* ru = (const float*)d_in[4];
    float* out = (float*)d_out;

    float* wpack          = (float*)d_ws;                            // 18432 B
    unsigned short* w1pb  = (unsigned short*)((char*)d_ws + 18432);  //  8192 B
    unsigned short* w2b   = (unsigned short*)((char*)d_ws + 26624);  //  4096 B
    float* w2row3         = (float*)((char*)d_ws + 30720);           //   512 B
    float* xn3buf         = (float*)((char*)d_ws + 32768);           // 8 MB (if available)

    prep_weights<<<1, 128, 0, stream>>>(w1, b1, w2, wpack, w1pb, w2b, w2row3);

    const size_t need = 32768 + (size_t)NB*65536*4;
    if (ws_size >= need) {
        dim3 grid1(IMW/32, IMH/8, NB);
        // ---- ablation probes (write scratch = xn3buf; real k1 overwrites it) ----
        k1_p_feat<<<grid1, K1T, 0, stream>>>(X, ru, xn3buf);
        k1_p_mlp<<<grid1, K1T, 0, stream>>>(X, ru, b1, w1pb, w2b, w2row3, xn3buf);
        // ---- real pipeline ----
        k1_dx<<<grid1, K1T, 0, stream>>>(X, ru, b1, wpack, w1pb, w2b, w2row3, xn3buf, out);
        dim3 grid2(IMW/32, IMH/16, NB);
        k2_mask<<<grid2, 512, 0, stream>>>(X, xn3buf, out);
    } else {
        dim3 grid(IMW/TILE, IMH/TILE, NB);
        nca_fused<<<grid, 512, 0, stream>>>(X, ru, b1, wpack, w1pb, w2b, w2row3, out);
    }
}

// Round 15
// 176.450 us; speedup vs baseline: 2.9218x; 2.9218x over previous
//
#include <hip/hip_runtime.h>
#include <hip/hip_bf16.h>
#include <cstddef>

#define NC 16
#define HID 128
#define IMH 256
#define IMW 256
#define NB 32
#define TILE 16
#define HR 18
#define XS 20
#define WROW 36
#define NPIX (HR*HR)
#define NTILES 21
#define FSTR 40      // fused-fallback feat stride
#define K1T 256      // k1 threads
#define K1FS 32      // k1 feat row stride (u16)

typedef __attribute__((ext_vector_type(8))) short bf16x8;
typedef __attribute__((ext_vector_type(4))) float f32x4;
typedef __attribute__((ext_vector_type(4))) unsigned u32x4;

union UB { u32x4 u; bf16x8 v; };

static __device__ __forceinline__ unsigned short f2bf(float x) {
    union { __hip_bfloat16 b; unsigned short u; } v;
    v.b = __float2bfloat16(x);
    return v.u;
}
static __device__ __forceinline__ float bf2f(unsigned short u) {
    union { __hip_bfloat16 b; unsigned short u; } v;
    v.u = u;
    return __bfloat162float(v.b);
}
static __device__ __forceinline__ unsigned pack2(float a, float b) {
    return (unsigned)f2bf(a) | ((unsigned)f2bf(b) << 16);
}

// ---------------- weight prep ----------------
__global__ void prep_weights(const float* __restrict__ w1,
                             const float* __restrict__ b1,
                             const float* __restrict__ w2,
                             float* __restrict__ wpack,
                             unsigned short* __restrict__ w1pb,
                             unsigned short* __restrict__ w2b,
                             float* __restrict__ w2row3) {
    int j = threadIdx.x;
    if (j >= HID) return;
    const int starts[18] = {0,3,6,9,12,15,16,18,21,24,27,30,32,33,36,39,42,45};
    const int lens[18]   = {3,3,3,3,3,1,2,3,3,3,3,2,1,3,3,3,3,3};
    float* row = wpack + j * WROW;
    row[0] = b1[j];
    float we[18];
    #pragma unroll
    for (int f = 0; f < 18; ++f) {
        float s = 0.f;
        for (int k = 0; k < lens[f]; ++k) s += w1[j*48 + starts[f] + k];
        we[f] = s;
        row[1+f] = s;
    }
    #pragma unroll
    for (int c = 0; c < NC; ++c) row[19+c] = w2[c*HID + j];
    row[35] = 0.f;
    #pragma unroll
    for (int g = 0; g < 4; ++g)
        #pragma unroll
        for (int r = 0; r < 8; ++r) {
            int k = g*8 + r;
            w1pb[(j*4 + g)*8 + r] = f2bf(k < 18 ? we[k] : 0.f);
        }
    #pragma unroll
    for (int c = 0; c < NC; ++c) w2b[c*HID + j] = f2bf(w2[c*HID + j]);
    w2row3[j] = w2[3*HID + j];
}

#define K1_TILE_BODY(LID)                                                        \
    do {                                                                         \
        const int row = wave*64 + (LID);                                         \
        bf16x8 fb = *(const bf16x8*)&feat[row][g*8];                             \
        f32x4 dacc = { 0.f, 0.f, 0.f, 0.f };                                     \
        float part = 0.f;                                                        \
        _Pragma("unroll")                                                        \
        for (int kc = 0; kc < 4; ++kc) {                                         \
            const int nt0 = 2*kc, nt1 = 2*kc + 1;                                \
            float4 bv0 = *(const float4*)(b1g + nt0*16 + g*4);                   \
            float4 bv1 = *(const float4*)(b1g + nt1*16 + g*4);                   \
            f32x4 ci0 = { bv0.x, bv0.y, bv0.z, bv0.w };                          \
            f32x4 ci1 = { bv1.x, bv1.y, bv1.z, bv1.w };                          \
            f32x4 acc0 = __builtin_amdgcn_mfma_f32_16x16x32_bf16(w1f[nt0], fb, ci0, 0, 0, 0); \
            f32x4 acc1 = __builtin_amdgcn_mfma_f32_16x16x32_bf16(w1f[nt1], fb, ci1, 0, 0, 0); \
            float4 wv0 = *(const float4*)(w2row3 + nt0*16 + g*4);                \
            float4 wv1 = *(const float4*)(w2row3 + nt1*16 + g*4);                \
            float h00 = fmaxf(acc0[0], 0.f), h01 = fmaxf(acc0[1], 0.f);          \
            float h02 = fmaxf(acc0[2], 0.f), h03 = fmaxf(acc0[3], 0.f);          \
            float h10 = fmaxf(acc1[0], 0.f), h11 = fmaxf(acc1[1], 0.f);          \
            float h12 = fmaxf(acc1[2], 0.f), h13 = fmaxf(acc1[3], 0.f);          \
            part = fmaf(wv0.x, h00, part); part = fmaf(wv0.y, h01, part);        \
            part = fmaf(wv0.z, h02, part); part = fmaf(wv0.w, h03, part);        \
            part = fmaf(wv1.x, h10, part); part = fmaf(wv1.y, h11, part);        \
            part = fmaf(wv1.z, h12, part); part = fmaf(wv1.w, h13, part);        \
            unsigned p00 = pack2(h00, h01), p01 = pack2(h02, h03);               \
            unsigned p10 = pack2(h10, h11), p11 = pack2(h12, h13);               \
            int a0s = __shfl((int)p00, srcA, 64);                                \
            int b0s = __shfl((int)p10, srcA, 64);                                \
            int a1s = __shfl((int)p01, srcA, 64);                                \
            int b1s = __shfl((int)p11, srcA, 64);                                \
            int a2s = __shfl((int)p00, srcB, 64);                                \
            int b2s = __shfl((int)p10, srcB, 64);                                \
            int a3s = __shfl((int)p01, srcB, 64);                                \
            int b3s = __shfl((int)p11, srcB, 64);                                \
            UB bu;                                                               \
            bu.u[0] = (unsigned)(hi ? b0s : a0s);                                \
            bu.u[1] = (unsigned)(hi ? b1s : a1s);                                \
            bu.u[2] = (unsigned)(hi ? b2s : a2s);                                \
            bu.u[3] = (unsigned)(hi ? b3s : a3s);                                \
            dacc = __builtin_amdgcn_mfma_f32_16x16x32_bf16(w2fA[kc], bu.v, dacc, 0, 0, 0); \
        }                                                                        \
        part += __shfl_xor(part, 16, 64);                                        \
        part += __shfl_xor(part, 32, 64);                                        \
        if (g == 0) *(float*)&feat[row][20] = part;                              \
        *(unsigned*)&feat[row][g*4]     = pack2(dacc[0], dacc[1]);               \
        *(unsigned*)&feat[row][g*4 + 2] = pack2(dacc[2], dacc[3]);               \
    } while (0)

// ================= K1: coalesced-staged features + compacted MFMA MLP =============
__global__ __launch_bounds__(K1T, 4)
void k1_dx(const float* __restrict__ X,
           const float* __restrict__ rand_u,
           const float* __restrict__ b1g,
           const float* __restrict__ wpack,
           const unsigned short* __restrict__ w1pb,
           const unsigned short* __restrict__ w2b,
           const float* __restrict__ w2row3,
           float* __restrict__ xn3buf,
           float* __restrict__ out) {
    __shared__ __align__(16) float sXc[5][8][32];                // 5120 B  (ch0-4, center only)
    __shared__ __align__(16) float sXh[11][10][40];              // 17600 B (ch5-15, halo, natural align)
    __shared__ __align__(16) unsigned short feat[K1T][K1FS];     // 16384 B
    __shared__ unsigned short sList[4][64];                      //   512 B

    const int t    = threadIdx.x;
    const int lx   = t & 31, ly = t >> 5;           // 32x8 pixel tile
    const int x0   = blockIdx.x*32;
    const int y0   = blockIdx.y*8;
    const int gx   = x0 + lx;
    const int gy   = y0 + ly;
    const int b    = blockIdx.z;
    const int lane = t & 63;
    const int c15  = lane & 15;
    const int g    = lane >> 4;
    const int wave = t >> 6;
    const int off  = gy*IMW + gx;

    const float* Xb = X + (size_t)b * NC * IMH * IMW;

    // hoisted: stochastic mask load overlaps staging
    const float ruv = rand_u[(size_t)b*65536 + off];

    // ---- staging: slot-flattened so LANE-ADJACENT slots are MEMORY-ADJACENT ----
    // Part A: ch0-4 center block, 5ch x 8rows x 8 float4 = 320 slots (always in-bounds)
    // Part B: ch5-15 halo block, 11ch x 10rows x 10 float4 = 1100 slots (zeros OOB)
    #pragma unroll
    for (int s = t; s < 1420; s += K1T) {
        if (s < 320) {
            const int ch = s >> 6, rem = s & 63, r = rem >> 3, j = rem & 7;
            float4 v = *(const float4*)(Xb + (size_t)ch*65536 + (size_t)(y0 + r)*IMW + x0 + 4*j);
            *(float4*)&sXc[ch][r][4*j] = v;
        } else {
            const int h = s - 320;
            const int ch = h / 100, rem = h - ch*100, r = rem / 10, j = rem - r*10;
            const int gyr = y0 + r - 1;
            const int col = x0 - 4 + 4*j;
            const float4 z = {0.f,0.f,0.f,0.f};
            const bool ok = (gyr >= 0 && gyr < IMH && col >= 0 && col <= 252);
            float4 v = ok ? *(const float4*)(Xb + (size_t)(5+ch)*65536 + (size_t)gyr*IMW + col) : z;
            *(float4*)&sXh[ch][r][4*j] = v;
        }
    }
    __syncthreads();
    asm volatile("" ::: "memory");   // keep frag loads below the staging phase

    // pinned weight fragments (48 VGPRs)
    bf16x8 w1f[8];
    #pragma unroll
    for (int nt = 0; nt < 8; ++nt)
        w1f[nt] = *(const bf16x8*)(w1pb + ((nt*16 + c15)*4 + g)*8);
    bf16x8 w2fA[4];
    #pragma unroll
    for (int kc = 0; kc < 4; ++kc)
        w2fA[kc] = *(const bf16x8*)(w2b + c15*128 + kc*32 + g*8);

    // ---- features (fp32) from LDS taps ----
    const int srh = ly + 1, sch = lx + 4;
    float f[18];
    #pragma unroll
    for (int c = 0; c < 5; ++c) f[c] = sXc[c][ly][lx];
    f[5] = sXh[0][srh][sch];
    #pragma unroll
    for (int i = 0; i < 5; ++i) {             // sobel_x ch5..9 -> f[6..10]  (sXh idx 0..4)
        float a  = sXh[i][srh-1][sch+1] - sXh[i][srh-1][sch-1];
        float bb = sXh[i][srh  ][sch+1] - sXh[i][srh  ][sch-1];
        float cc = sXh[i][srh+1][sch+1] - sXh[i][srh+1][sch-1];
        f[6+i] = (a + 2.f*bb + cc) * 0.125f;
    }
    {                                         // ch10 (sXh idx 5) shared taps -> f[11], f[12]
        float tl = sXh[5][srh-1][sch-1], tc = sXh[5][srh-1][sch], tr = sXh[5][srh-1][sch+1];
        float ml = sXh[5][srh][sch-1],                            mr = sXh[5][srh][sch+1];
        float bl = sXh[5][srh+1][sch-1], bc = sXh[5][srh+1][sch], br = sXh[5][srh+1][sch+1];
        f[11] = ((tr-tl) + 2.f*(mr-ml) + (br-bl)) * 0.125f;
        f[12] = ((bl + 2.f*bc + br) - (tl + 2.f*tc + tr)) * 0.125f;
    }
    #pragma unroll
    for (int i = 0; i < 5; ++i) {             // sobel_y ch11..15 -> f[13..17] (sXh idx 6..10)
        const int ch = 6 + i;
        float tp = sXh[ch][srh-1][sch-1] + 2.f*sXh[ch][srh-1][sch] + sXh[ch][srh-1][sch+1];
        float bt = sXh[ch][srh+1][sch-1] + 2.f*sXh[ch][srh+1][sch] + sXh[ch][srh+1][sch+1];
        f[13+i] = (bt - tp) * 0.125f;
    }

    {   // pack features (cols 18..31 zeroed)
        unsigned w[9];
        #pragma unroll
        for (int q = 0; q < 9; ++q) w[q] = pack2(f[2*q], f[2*q+1]);
        u32x4 v0 = { w[0], w[1], w[2], w[3] };
        u32x4 v1 = { w[4], w[5], w[6], w[7] };
        u32x4 v2 = { w[8], 0u, 0u, 0u };
        u32x4 z4 = { 0u, 0u, 0u, 0u };
        *(u32x4*)&feat[t][0]  = v0;
        *(u32x4*)&feat[t][8]  = v1;
        *(u32x4*)&feat[t][16] = v2;
        *(u32x4*)&feat[t][24] = z4;
    }

    // ---- per-wave active-pixel compaction ----
    const bool active = (ruv < 0.5f);
    const unsigned long long wm = __ballot(active);
    const int count = __popcll(wm);
    const int ntiles = (count + 15) >> 4;
    if (active) {
        const int pf = __popcll(wm & ((1ull << lane) - 1ull));
        sList[wave][pf] = (unsigned short)lane;
    }
    asm volatile("s_waitcnt lgkmcnt(0)" ::: "memory");
    __builtin_amdgcn_sched_barrier(0);

    // tail slots alias an INACTIVE pixel (feat row never dx-overlaid) — R13 fix
    const int safe = (count < 64) ? ((int)__ffsll((long long)(~wm)) - 1) : 0;
    int lid0 = safe, lid1 = safe, lid2 = safe, lid3 = safe;
    if (0*16 + c15 < count) lid0 = sList[wave][0*16 + c15];
    if (1*16 + c15 < count) lid1 = sList[wave][1*16 + c15];
    if (2*16 + c15 < count) lid2 = sList[wave][2*16 + c15];
    if (3*16 + c15 < count) lid3 = sList[wave][3*16 + c15];

    const int srcA = ((( g<<1     ) & 3) << 4) + c15;
    const int srcB = ((((g<<1) + 1) & 3) << 4) + c15;
    const bool hi  = (g >= 2);

    if (ntiles > 0) K1_TILE_BODY(lid0);
    if (ntiles > 1) K1_TILE_BODY(lid1);
    if (ntiles > 2) K1_TILE_BODY(lid2);
    if (ntiles > 3) K1_TILE_BODY(lid3);

    asm volatile("s_waitcnt lgkmcnt(0)" ::: "memory");
    __builtin_amdgcn_sched_barrier(0);

    // ---- epilogue ----
    const float X3 = sXc[3][ly][lx];
    float xn3 = X3;
    if (active) {
        float dx3 = *(const float*)&feat[t][20];
        xn3 = dx3 + X3;
    }

    // WAVE-COOPERATIVE exact fp32 fallback near the alpha threshold (rare).
    {
        const bool need = active && (fabsf(xn3 - 0.1f) < 1e-3f);
        unsigned long long nm = __ballot(need);
        if (nm != 0ull) {
            const int j0 = lane*2, j1 = lane*2 + 1;
            while (nm != 0ull) {
                const int src = (int)__ffsll((long long)nm) - 1;
                nm &= nm - 1ull;
                const int off_e = __shfl(off, src, 64);
                const int gx_e = off_e & 255, gy_e = off_e >> 8;
                const bool yle = gy_e > 0, yhe = gy_e < IMH-1;
                const bool xle = gx_e > 0, xhe = gx_e < IMW-1;
                float fv = 0.f;
                if (lane < 6) {
                    fv = Xb[lane*65536 + off_e];
                } else if (lane < 12) {
                    const float* P = Xb + (lane-1)*65536 + off_e;
                    float tl = (yle&&xle) ? P[-257] : 0.f, tr = (yle&&xhe) ? P[-255] : 0.f;
                    float ml = xle ? P[-1] : 0.f,          mr = xhe ? P[1] : 0.f;
                    float bl = (yhe&&xle) ? P[255] : 0.f,  br = (yhe&&xhe) ? P[257] : 0.f;
                    fv = ((tr-tl) + 2.f*(mr-ml) + (br-bl)) * 0.125f;
                } else if (lane < 18) {
                    const float* P = Xb + (lane-2)*65536 + off_e;
                    float tl = (yle&&xle) ? P[-257] : 0.f, tc = yle ? P[-256] : 0.f, tr = (yle&&xhe) ? P[-255] : 0.f;
                    float bl = (yhe&&xle) ? P[255]  : 0.f, bc = yhe ? P[256]  : 0.f, br = (yhe&&xhe) ? P[257]  : 0.f;
                    fv = ((bl + 2.f*bc + br) - (tl + 2.f*tc + tr)) * 0.125f;
                }
                float fe[18];
                #pragma unroll
                for (int k = 0; k < 18; ++k) fe[k] = __shfl(fv, k, 64);
                const float* r0 = wpack + j0*WROW;
                const float* r1 = wpack + j1*WROW;
                float h0 = r0[0], h1 = r1[0];
                #pragma unroll
                for (int k = 0; k < 18; ++k) {
                    h0 = fmaf(r0[1+k], fe[k], h0);
                    h1 = fmaf(r1[1+k], fe[k], h1);
                }
                h0 = fmaxf(h0, 0.f); h1 = fmaxf(h1, 0.f);
                float d = fmaf(r0[22], h0, r1[22]*h1);
                #pragma unroll
                for (int o = 1; o < 64; o <<= 1) d += __shfl_xor(d, o, 64);
                if (lane == src) xn3 = __shfl(X3, src, 64) + d;
            }
        }
    }

    xn3buf[(size_t)b*65536 + off] = xn3;
    u32x4 da = *(const u32x4*)&feat[t][0];
    u32x4 db = *(const u32x4*)&feat[t][8];
    float* ob = out + (size_t)b*NC*65536 + off;
    unsigned dw[8] = { da.x, da.y, da.z, da.w, db.x, db.y, db.z, db.w };
    #pragma unroll
    for (int c = 0; c < NC; ++c) {
        unsigned short u = (c & 1) ? (unsigned short)(dw[c>>1] >> 16)
                                   : (unsigned short)(dw[c>>1] & 0xffff);
        const float xc = (c < 5) ? sXc[c][ly][lx] : sXh[c-5][srh][sch];
        float val = (c == 3) ? xn3 : (active ? (bf2f(u) + xc) : xc);
        ob[c*65536] = val;
    }
}

// ================= K2: live mask, out *= live =================
__global__ __launch_bounds__(512, 4)
void k2_mask(const float* __restrict__ X,
             const float* __restrict__ xn3buf,
             float* out) {
    __shared__ float sPre[HR][34];
    __shared__ float sPost[HR][34];

    const int t  = threadIdx.x;
    const int x0 = blockIdx.x*32, y0 = blockIdx.y*16;
    const int b  = blockIdx.z;

    const float* X3p = X + (size_t)b*NC*65536 + 3*65536;
    const float* Pp  = xn3buf + (size_t)b*65536;
    for (int e = t; e < HR*34; e += 512) {
        int row = e / 34, col = e - row*34;
        int gy = y0 + row - 1, gx = x0 + col - 1;
        bool ok = (gy >= 0 && gy < IMH && gx >= 0 && gx < IMW);
        int idx = (gy & 255)*IMW + (gx & 255);
        sPre[row][col]  = ok ? X3p[idx] : 0.f;
        sPost[row][col] = ok ? Pp[idx]  : 0.f;
    }
    __syncthreads();

    const int lx = t & 31, ly = t >> 5;
    float mpre = -1.f, mpost = -1.f;
    #pragma unroll
    for (int dy = 0; dy < 3; ++dy)
        #pragma unroll
        for (int dxx = 0; dxx < 3; ++dxx) {
            mpre  = fmaxf(mpre,  sPre[ly+dy][lx+dxx]);
            mpost = fmaxf(mpost, sPost[ly+dy][lx+dxx]);
        }
    const float live = (mpre > 0.1f && mpost > 0.1f) ? 1.f : 0.f;
    const int off = (y0+ly)*IMW + (x0+lx);
    float* ob = out + (size_t)b*NC*65536 + off;
    #pragma unroll
    for (int c = 0; c < NC; ++c) {
        float v = ob[c*65536];
        ob[c*65536] = v * live;
    }
}

// ================= fallback fused kernel (ws too small; same as R7) ===============
__global__ __launch_bounds__(512, 3)
void nca_fused(const float* __restrict__ X,
               const float* __restrict__ rand_u,
               const float* __restrict__ b1g,
               const float* __restrict__ wpack,
               const unsigned short* __restrict__ w1pb,
               const unsigned short* __restrict__ w2b,
               const float* __restrict__ w2row3,
               float* __restrict__ out) {
    __shared__ __align__(16) float sX[NC][XS][XS];
    __shared__ __align__(16) unsigned short feat[336][FSTR];
    __shared__ __align__(16) float sB1[HID];
    __shared__ __align__(16) float sW23[HID];

    const int t    = threadIdx.x;
    const int x0   = blockIdx.x * TILE;
    const int y0   = blockIdx.y * TILE;
    const int b    = blockIdx.z;
    const int lane = t & 63;
    const int c15  = lane & 15;
    const int g    = lane >> 4;
    const int wave = t >> 6;

    const float* Xb = X + (size_t)b * NC * IMH * IMW;

    if (t < HID) { sB1[t] = b1g[t]; sW23[t] = w2row3[t]; }

    if (t < NC*XS) {
        int ch = t / XS, row = t % XS;
        int gy = y0 + row - 2;
        bool yok = (gy >= 0 && gy < IMH);
        const float* src = Xb + (size_t)ch*IMH*IMW + (size_t)(yok ? gy : 0)*IMW;
        float4 z = {0.f,0.f,0.f,0.f};
        float buf[24];
        *(float4*)&buf[0]  = (yok && x0 > 0)   ? *(const float4*)(src + x0 - 4)  : z;
        *(float4*)&buf[4]  = yok               ? *(const float4*)(src + x0)      : z;
        *(float4*)&buf[8]  = yok               ? *(const float4*)(src + x0 + 4)  : z;
        *(float4*)&buf[12] = yok               ? *(const float4*)(src + x0 + 8)  : z;
        *(float4*)&buf[16] = yok               ? *(const float4*)(src + x0 + 12) : z;
        *(float4*)&buf[20] = (yok && x0 < 240) ? *(const float4*)(src + x0 + 16) : z;
        #pragma unroll
        for (int k = 0; k < 5; ++k) {
            float4 v = { buf[4*k+2], buf[4*k+3], buf[4*k+4], buf[4*k+5] };
            *(float4*)&sX[ch][row][4*k] = v;
        }
    }
    float m_reg = 0.f;
    if (t < NPIX) {
        int py = t / HR, px = t - py*HR;
        int gy = y0 + py - 1, gx = x0 + px - 1;
        if (gy >= 0 && gy < IMH && gx >= 0 && gx < IMW)
            m_reg = (rand_u[((size_t)b << 16) + (gy << 8) + gx] < 0.5f) ? 1.f : 0.f;
    }
    __syncthreads();

    if (t < NPIX) {
        const int py = t / HR, px = t - py*HR;
        const int cy = py + 1, cx = px + 1;
        float f[18];
        #pragma unroll
        for (int c = 0; c < 6; ++c) f[c] = sX[c][cy][cx];
        #pragma unroll
        for (int i = 0; i < 6; ++i) {
            const int ch = 5 + i;
            float a  = sX[ch][cy-1][cx+1] - sX[ch][cy-1][cx-1];
            float bb = sX[ch][cy  ][cx+1] - sX[ch][cy  ][cx-1];
            float cc = sX[ch][cy+1][cx+1] - sX[ch][cy+1][cx-1];
            f[6+i] = (a + 2.f*bb + cc) * 0.125f;
        }
        #pragma unroll
        for (int i = 0; i < 6; ++i) {
            const int ch = 10 + i;
            float tp = sX[ch][cy-1][cx-1] + 2.f*sX[ch][cy-1][cx] + sX[ch][cy-1][cx+1];
            float bt = sX[ch][cy+1][cx-1] + 2.f*sX[ch][cy+1][cx] + sX[ch][cy+1][cx+1];
            f[12+i] = (bt - tp) * 0.125f;
        }
        unsigned w[9];
        #pragma unroll
        for (int q = 0; q < 9; ++q) w[q] = pack2(f[2*q], f[2*q+1]);
        u32x4 v0 = { w[0], w[1], w[2], w[3] };
        u32x4 v1 = { w[4], w[5], w[6], w[7] };
        u32x4 v2 = { w[8], 0u, 0u, 0u };
        u32x4 z4 = { 0u, 0u, 0u, 0u };
        *(u32x4*)&feat[t][0]  = v0;
        *(u32x4*)&feat[t][8]  = v1;
        *(u32x4*)&feat[t][16] = v2;
        *(u32x4*)&feat[t][24] = z4;
    } else if (t < 336) {
        u32x4 z4 = { 0u, 0u, 0u, 0u };
        *(u32x4*)&feat[t][0]  = z4;
        *(u32x4*)&feat[t][8]  = z4;
        *(u32x4*)&feat[t][16] = z4;
        *(u32x4*)&feat[t][24] = z4;
    }
    __syncthreads();

    const int srcA = ((( g<<1     ) & 3) << 4) + c15;
    const int srcB = ((((g<<1) + 1) & 3) << 4) + c15;
    const bool hi  = (g >= 2);
    #pragma unroll 1
    for (int tile = wave; tile < NTILES; tile += 8) {
        const unsigned short* w1p_ = w1pb;
        const unsigned short* w2p_ = w2b;
        asm volatile("" : "+v"(w1p_), "+v"(w2p_));

        bf16x8 fb = *(const bf16x8*)&feat[tile*16 + c15][g*8];
        f32x4 dacc = { 0.f, 0.f, 0.f, 0.f };
        float part = 0.f;
        #pragma unroll
        for (int kc = 0; kc < 4; ++kc) {
            const int nt0 = 2*kc, nt1 = 2*kc + 1;
            bf16x8 a0 = *(const bf16x8*)(w1p_ + ((nt0*16 + c15)*4 + g)*8);
            bf16x8 a1 = *(const bf16x8*)(w1p_ + ((nt1*16 + c15)*4 + g)*8);
            float4 bv0 = *(const float4*)&sB1[nt0*16 + g*4];
            float4 bv1 = *(const float4*)&sB1[nt1*16 + g*4];
            f32x4 ci0 = { bv0.x, bv0.y, bv0.z, bv0.w };
            f32x4 ci1 = { bv1.x, bv1.y, bv1.z, bv1.w };
            f32x4 acc0 = __builtin_amdgcn_mfma_f32_16x16x32_bf16(a0, fb, ci0, 0, 0, 0);
            f32x4 acc1 = __builtin_amdgcn_mfma_f32_16x16x32_bf16(a1, fb, ci1, 0, 0, 0);
            float4 wv0 = *(const float4*)&sW23[nt0*16 + g*4];
            float4 wv1 = *(const float4*)&sW23[nt1*16 + g*4];
            float h00 = fmaxf(acc0[0], 0.f), h01 = fmaxf(acc0[1], 0.f);
            float h02 = fmaxf(acc0[2], 0.f), h03 = fmaxf(acc0[3], 0.f);
            float h10 = fmaxf(acc1[0], 0.f), h11 = fmaxf(acc1[1], 0.f);
            float h12 = fmaxf(acc1[2], 0.f), h13 = fmaxf(acc1[3], 0.f);
            part = fmaf(wv0.x, h00, part); part = fmaf(wv0.y, h01, part);
            part = fmaf(wv0.z, h02, part); part = fmaf(wv0.w, h03, part);
            part = fmaf(wv1.x, h10, part); part = fmaf(wv1.y, h11, part);
            part = fmaf(wv1.z, h12, part); part = fmaf(wv1.w, h13, part);
            unsigned p00 = pack2(h00, h01), p01 = pack2(h02, h03);
            unsigned p10 = pack2(h10, h11), p11 = pack2(h12, h13);
            int a0s = __shfl((int)p00, srcA, 64);
            int b0s = __shfl((int)p10, srcA, 64);
            int a1s = __shfl((int)p01, srcA, 64);
            int b1s = __shfl((int)p11, srcA, 64);
            int a2s = __shfl((int)p00, srcB, 64);
            int b2s = __shfl((int)p10, srcB, 64);
            int a3s = __shfl((int)p01, srcB, 64);
            int b3s = __shfl((int)p11, srcB, 64);
            UB bu;
            bu.u[0] = (unsigned)(hi ? b0s : a0s);
            bu.u[1] = (unsigned)(hi ? b1s : a1s);
            bu.u[2] = (unsigned)(hi ? b2s : a2s);
            bu.u[3] = (unsigned)(hi ? b3s : a3s);
            bf16x8 w2a = *(const bf16x8*)(w2p_ + c15*128 + kc*32 + g*8);
            dacc = __builtin_amdgcn_mfma_f32_16x16x32_bf16(w2a, bu.v, dacc, 0, 0, 0);
        }
        part += __shfl_xor(part, 16, 64);
        part += __shfl_xor(part, 32, 64);
        if (g == 0) *(float*)&feat[tile*16 + c15][34] = part;
        *(unsigned*)&feat[tile*16 + c15][g*4]     = pack2(dacc[0], dacc[1]);
        *(unsigned*)&feat[tile*16 + c15][g*4 + 2] = pack2(dacc[2], dacc[3]);
    }
    __syncthreads();

    if (t < NPIX) {
        const int py = t / HR, px = t - py*HR;
        const int cy = py + 1, cx = px + 1;
        float dx3 = *(const float*)&feat[t][34];
        float X3  = sX[3][cy][cx];
        float xn3 = fmaf(dx3, m_reg, X3);
        if (m_reg != 0.f && fabsf(xn3 - 0.1f) < 1e-3f) {
            float f[18];
            #pragma unroll
            for (int c = 0; c < 6; ++c) f[c] = sX[c][cy][cx];
            #pragma unroll
            for (int i = 0; i < 6; ++i) {
                const int ch = 5 + i;
                f[6+i] = ((sX[ch][cy-1][cx+1] - sX[ch][cy-1][cx-1])
                        + 2.f*(sX[ch][cy][cx+1] - sX[ch][cy][cx-1])
                        + (sX[ch][cy+1][cx+1] - sX[ch][cy+1][cx-1])) * 0.125f;
            }
            #pragma unroll
            for (int i = 0; i < 6; ++i) {
                const int ch = 10 + i;
                f[12+i] = ((sX[ch][cy+1][cx-1] + 2.f*sX[ch][cy+1][cx] + sX[ch][cy+1][cx+1])
                         - (sX[ch][cy-1][cx-1] + 2.f*sX[ch][cy-1][cx] + sX[ch][cy-1][cx+1])) * 0.125f;
            }
            float d3 = 0.f;
            for (int j = 0; j < HID; ++j) {
                const float* row = wpack + j*WROW;
                float hj = row[0];
                #pragma unroll
                for (int k = 0; k < 18; ++k) hj = fmaf(row[1+k], f[k], hj);
                hj = fmaxf(hj, 0.f);
                d3 = fmaf(row[22], hj, d3);
            }
            xn3 = X3 + d3;
        }
        *(float*)&feat[t][32] = xn3;
    }
    __syncthreads();

    if (t < NPIX) {
        const int py = t / HR, px = t - py*HR;
        if (py >= 1 && py <= TILE && px >= 1 && px <= TILE) {
            float mpre = -1.f, mpost = -1.f;
            #pragma unroll
            for (int dy = 0; dy < 3; ++dy)
                #pragma unroll
                for (int dxx = 0; dxx < 3; ++dxx) {
                    mpre  = fmaxf(mpre,  sX[3][py+dy][px+dxx]);
                    mpost = fmaxf(mpost, *(const float*)&feat[(py-1+dy)*HR + (px-1+dxx)][32]);
                }
            const float live = (mpre > 0.1f && mpost > 0.1f) ? 1.f : 0.f;
            const int gy = y0 + py - 1, gx = x0 + px - 1;
            float* ob = out + ((size_t)b*NC)*IMH*IMW + (size_t)gy*IMW + gx;
            u32x4 da = *(const u32x4*)&feat[t][0];
            u32x4 db = *(const u32x4*)&feat[t][8];
            float xn3 = *(const float*)&feat[t][32];
            unsigned dw[8] = { da.x, da.y, da.z, da.w, db.x, db.y, db.z, db.w };
            #pragma unroll
            for (int c = 0; c < NC; ++c) {
                unsigned short u = (c & 1) ? (unsigned short)(dw[c>>1] >> 16)
                                           : (unsigned short)(dw[c>>1] & 0xffff);
                float val = (c == 3) ? xn3
                                     : fmaf(bf2f(u), m_reg, sX[c][py+1][px+1]);
                ob[(size_t)c*IMH*IMW] = val * live;
            }
        }
    }
}

extern "C" void kernel_launch(void* const* d_in, const int* in_sizes, int n_in,
                              void* d_out, int out_size, void* d_ws, size_t ws_size,
                              hipStream_t stream) {
    const float* X  = (const float*)d_in[0];
    const float* w1 = (const float*)d_in[1];
    const float* b1 = (const float*)d_in[2];
    const float* w2 = (const float*)d_in[3];
    const float* ru = (const float*)d_in[4];
    float* out = (float*)d_out;

    float* wpack          = (float*)d_ws;                            // 18432 B
    unsigned short* w1pb  = (unsigned short*)((char*)d_ws + 18432);  //  8192 B
    unsigned short* w2b   = (unsigned short*)((char*)d_ws + 26624);  //  4096 B
    float* w2row3         = (float*)((char*)d_ws + 30720);           //   512 B
    float* xn3buf         = (float*)((char*)d_ws + 32768);           // 8 MB (if available)

    prep_weights<<<1, 128, 0, stream>>>(w1, b1, w2, wpack, w1pb, w2b, w2row3);

    const size_t need = 32768 + (size_t)NB*65536*4;
    if (ws_size >= need) {
        dim3 grid1(IMW/32, IMH/8, NB);
        k1_dx<<<grid1, K1T, 0, stream>>>(X, ru, b1, wpack, w1pb, w2b, w2row3, xn3buf, out);
        dim3 grid2(IMW/32, IMH/16, NB);
        k2_mask<<<grid2, 512, 0, stream>>>(X, xn3buf, out);
    } else {
        dim3 grid(IMW/TILE, IMH/TILE, NB);
        nca_fused<<<grid, 512, 0, stream>>>(X, ru, b1, wpack, w1pb, w2b, w2row3, out);
    }
}

// Round 16
// 153.142 us; speedup vs baseline: 3.3665x; 1.1522x over previous
//
#include <hip/hip_runtime.h>
#include <hip/hip_bf16.h>
#include <cstddef>

#define NC 16
#define HID 128
#define IMH 256
#define IMW 256
#define NB 32
#define TILE 16
#define HR 18
#define XS 20
#define WROW 36
#define NPIX (HR*HR)
#define NTILES 21
#define FSTR 40      // fused-fallback feat stride
#define K1T 256      // k1 threads
#define K1FS 24      // k1 feat row stride (u16): cols 0-15 feats/dx, 16-23 tail (f16,f17,0..)

typedef __attribute__((ext_vector_type(8))) short bf16x8;
typedef __attribute__((ext_vector_type(4))) float f32x4;
typedef __attribute__((ext_vector_type(4))) unsigned u32x4;

union UB { u32x4 u; bf16x8 v; };

static __device__ __forceinline__ unsigned short f2bf(float x) {
    union { __hip_bfloat16 b; unsigned short u; } v;
    v.b = __float2bfloat16(x);
    return v.u;
}
static __device__ __forceinline__ float bf2f(unsigned short u) {
    union { __hip_bfloat16 b; unsigned short u; } v;
    v.u = u;
    return __bfloat162float(v.b);
}
static __device__ __forceinline__ unsigned pack2(float a, float b) {
    return (unsigned)f2bf(a) | ((unsigned)f2bf(b) << 16);
}

// ---------------- weight prep ----------------
__global__ void prep_weights(const float* __restrict__ w1,
                             const float* __restrict__ b1,
                             const float* __restrict__ w2,
                             float* __restrict__ wpack,
                             unsigned short* __restrict__ w1pb,
                             unsigned short* __restrict__ w2b,
                             float* __restrict__ w2row3) {
    int j = threadIdx.x;
    if (j >= HID) return;
    const int starts[18] = {0,3,6,9,12,15,16,18,21,24,27,30,32,33,36,39,42,45};
    const int lens[18]   = {3,3,3,3,3,1,2,3,3,3,3,2,1,3,3,3,3,3};
    float* row = wpack + j * WROW;
    row[0] = b1[j];
    float we[18];
    #pragma unroll
    for (int f = 0; f < 18; ++f) {
        float s = 0.f;
        for (int k = 0; k < lens[f]; ++k) s += w1[j*48 + starts[f] + k];
        we[f] = s;
        row[1+f] = s;
    }
    #pragma unroll
    for (int c = 0; c < NC; ++c) row[19+c] = w2[c*HID + j];
    row[35] = 0.f;
    #pragma unroll
    for (int g = 0; g < 4; ++g)
        #pragma unroll
        for (int r = 0; r < 8; ++r) {
            int k = g*8 + r;
            w1pb[(j*4 + g)*8 + r] = f2bf(k < 18 ? we[k] : 0.f);
        }
    #pragma unroll
    for (int c = 0; c < NC; ++c) w2b[c*HID + j] = f2bf(w2[c*HID + j]);
    w2row3[j] = w2[3*HID + j];
}

#define K1_TILE_BODY(LID)                                                        \
    do {                                                                         \
        const int row = wave*64 + (LID);                                         \
        bf16x8 fb;                                                               \
        if (g < 3) fb = *(const bf16x8*)&feat[row][g*8];                         \
        else { UB zz; zz.u = (u32x4){0u,0u,0u,0u}; fb = zz.v; }                  \
        f32x4 dacc = { 0.f, 0.f, 0.f, 0.f };                                     \
        float part = 0.f;                                                        \
        _Pragma("unroll")                                                        \
        for (int kc = 0; kc < 4; ++kc) {                                         \
            const int nt0 = 2*kc, nt1 = 2*kc + 1;                                \
            float4 bv0 = *(const float4*)(b1g + nt0*16 + g*4);                   \
            float4 bv1 = *(const float4*)(b1g + nt1*16 + g*4);                   \
            f32x4 ci0 = { bv0.x, bv0.y, bv0.z, bv0.w };                          \
            f32x4 ci1 = { bv1.x, bv1.y, bv1.z, bv1.w };                          \
            f32x4 acc0 = __builtin_amdgcn_mfma_f32_16x16x32_bf16(w1f[nt0], fb, ci0, 0, 0, 0); \
            f32x4 acc1 = __builtin_amdgcn_mfma_f32_16x16x32_bf16(w1f[nt1], fb, ci1, 0, 0, 0); \
            float4 wv0 = *(const float4*)(w2row3 + nt0*16 + g*4);                \
            float4 wv1 = *(const float4*)(w2row3 + nt1*16 + g*4);                \
            float h00 = fmaxf(acc0[0], 0.f), h01 = fmaxf(acc0[1], 0.f);          \
            float h02 = fmaxf(acc0[2], 0.f), h03 = fmaxf(acc0[3], 0.f);          \
            float h10 = fmaxf(acc1[0], 0.f), h11 = fmaxf(acc1[1], 0.f);          \
            float h12 = fmaxf(acc1[2], 0.f), h13 = fmaxf(acc1[3], 0.f);          \
            part = fmaf(wv0.x, h00, part); part = fmaf(wv0.y, h01, part);        \
            part = fmaf(wv0.z, h02, part); part = fmaf(wv0.w, h03, part);        \
            part = fmaf(wv1.x, h10, part); part = fmaf(wv1.y, h11, part);        \
            part = fmaf(wv1.z, h12, part); part = fmaf(wv1.w, h13, part);        \
            unsigned p00 = pack2(h00, h01), p01 = pack2(h02, h03);               \
            unsigned p10 = pack2(h10, h11), p11 = pack2(h12, h13);               \
            int a0s = __shfl((int)p00, srcA, 64);                                \
            int b0s = __shfl((int)p10, srcA, 64);                                \
            int a1s = __shfl((int)p01, srcA, 64);                                \
            int b1s = __shfl((int)p11, srcA, 64);                                \
            int a2s = __shfl((int)p00, srcB, 64);                                \
            int b2s = __shfl((int)p10, srcB, 64);                                \
            int a3s = __shfl((int)p01, srcB, 64);                                \
            int b3s = __shfl((int)p11, srcB, 64);                                \
            UB bu;                                                               \
            bu.u[0] = (unsigned)(hi ? b0s : a0s);                                \
            bu.u[1] = (unsigned)(hi ? b1s : a1s);                                \
            bu.u[2] = (unsigned)(hi ? b2s : a2s);                                \
            bu.u[3] = (unsigned)(hi ? b3s : a3s);                                \
            dacc = __builtin_amdgcn_mfma_f32_16x16x32_bf16(w2fA[kc], bu.v, dacc, 0, 0, 0); \
        }                                                                        \
        part += __shfl_xor(part, 16, 64);                                        \
        part += __shfl_xor(part, 32, 64);                                        \
        if (g == 0) *(float*)&feat[row][20] = part;                              \
        *(unsigned*)&feat[row][g*4]     = pack2(dacc[0], dacc[1]);               \
        *(unsigned*)&feat[row][g*4 + 2] = pack2(dacc[2], dacc[3]);               \
    } while (0)

// ================= K1: reg+LDS staged features + compacted MFMA MLP ===============
__global__ __launch_bounds__(K1T, 5)
void k1_dx(const float* __restrict__ X,
           const float* __restrict__ rand_u,
           const float* __restrict__ b1g,
           const float* __restrict__ wpack,
           const unsigned short* __restrict__ w1pb,
           const unsigned short* __restrict__ w2b,
           const float* __restrict__ w2row3,
           float* __restrict__ xn3buf,
           float* __restrict__ out) {
    __shared__ __align__(16) float sXh[11][10][40];              // 17600 B (ch5-15, halo)
    __shared__ __align__(16) unsigned short feat[K1T][K1FS];     // 12288 B
    __shared__ unsigned short sList[4][64];                      //   512 B

    const int t    = threadIdx.x;
    const int lx   = t & 31, ly = t >> 5;           // 32x8 pixel tile
    const int x0   = blockIdx.x*32;
    const int y0   = blockIdx.y*8;
    const int gx   = x0 + lx;
    const int gy   = y0 + ly;
    const int b    = blockIdx.z;
    const int lane = t & 63;
    const int c15  = lane & 15;
    const int g    = lane >> 4;
    const int wave = t >> 6;
    const int off  = gy*IMW + gx;

    const float* Xb = X + (size_t)b * NC * IMH * IMW;

    // hoisted loads: mask + center values of ch0-4 (perfectly coalesced dwords)
    const float ruv = rand_u[(size_t)b*65536 + off];
    float xr[5];
    #pragma unroll
    for (int c = 0; c < 5; ++c) xr[c] = Xb[c*65536 + off];

    // ---- staging: ch5-15 halo block, slot-flattened (lane-adjacent = mem-adjacent) ----
    // 11ch x 10rows x 10 float4 = 1100 slots, zeros OOB
    #pragma unroll
    for (int s = t; s < 1100; s += K1T) {
        const int ch = s / 100, rem = s - ch*100, r = rem / 10, j = rem - r*10;
        const int gyr = y0 + r - 1;
        const int col = x0 - 4 + 4*j;
        const float4 z = {0.f,0.f,0.f,0.f};
        const bool ok = (gyr >= 0 && gyr < IMH && col >= 0 && col <= 252);
        float4 v = ok ? *(const float4*)(Xb + (size_t)(5+ch)*65536 + (size_t)gyr*IMW + col) : z;
        *(float4*)&sXh[ch][r][4*j] = v;
    }
    __syncthreads();
    asm volatile("" ::: "memory");   // keep frag loads below the staging phase

    // pinned weight fragments (48 VGPRs)
    bf16x8 w1f[8];
    #pragma unroll
    for (int nt = 0; nt < 8; ++nt)
        w1f[nt] = *(const bf16x8*)(w1pb + ((nt*16 + c15)*4 + g)*8);
    bf16x8 w2fA[4];
    #pragma unroll
    for (int kc = 0; kc < 4; ++kc)
        w2fA[kc] = *(const bf16x8*)(w2b + c15*128 + kc*32 + g*8);

    // ---- features (fp32): ch0-4 from registers, ch5-15 from LDS ----
    const int srh = ly + 1, sch = lx + 4;
    float f[18];
    #pragma unroll
    for (int c = 0; c < 5; ++c) f[c] = xr[c];
    f[5] = sXh[0][srh][sch];
    #pragma unroll
    for (int i = 0; i < 5; ++i) {             // sobel_x ch5..9 -> f[6..10]  (sXh idx 0..4)
        float a  = sXh[i][srh-1][sch+1] - sXh[i][srh-1][sch-1];
        float bb = sXh[i][srh  ][sch+1] - sXh[i][srh  ][sch-1];
        float cc = sXh[i][srh+1][sch+1] - sXh[i][srh+1][sch-1];
        f[6+i] = (a + 2.f*bb + cc) * 0.125f;
    }
    {                                         // ch10 (sXh idx 5) shared taps -> f[11], f[12]
        float tl = sXh[5][srh-1][sch-1], tc = sXh[5][srh-1][sch], tr = sXh[5][srh-1][sch+1];
        float ml = sXh[5][srh][sch-1],                            mr = sXh[5][srh][sch+1];
        float bl = sXh[5][srh+1][sch-1], bc = sXh[5][srh+1][sch], br = sXh[5][srh+1][sch+1];
        f[11] = ((tr-tl) + 2.f*(mr-ml) + (br-bl)) * 0.125f;
        f[12] = ((bl + 2.f*bc + br) - (tl + 2.f*tc + tr)) * 0.125f;
    }
    #pragma unroll
    for (int i = 0; i < 5; ++i) {             // sobel_y ch11..15 -> f[13..17] (sXh idx 6..10)
        const int ch = 6 + i;
        float tp = sXh[ch][srh-1][sch-1] + 2.f*sXh[ch][srh-1][sch] + sXh[ch][srh-1][sch+1];
        float bt = sXh[ch][srh+1][sch-1] + 2.f*sXh[ch][srh+1][sch] + sXh[ch][srh+1][sch+1];
        f[13+i] = (bt - tp) * 0.125f;
    }

    {   // pack features: cols 0-17 = f, cols 18-23 zeros (g=3 frag handled as reg-zero)
        unsigned w[9];
        #pragma unroll
        for (int q = 0; q < 9; ++q) w[q] = pack2(f[2*q], f[2*q+1]);
        u32x4 v0 = { w[0], w[1], w[2], w[3] };
        u32x4 v1 = { w[4], w[5], w[6], w[7] };
        u32x4 v2 = { w[8], 0u, 0u, 0u };
        *(u32x4*)&feat[t][0]  = v0;
        *(u32x4*)&feat[t][8]  = v1;
        *(u32x4*)&feat[t][16] = v2;
    }

    // ---- per-wave active-pixel compaction ----
    const bool active = (ruv < 0.5f);
    const unsigned long long wm = __ballot(active);
    const int count = __popcll(wm);
    const int ntiles = (count + 15) >> 4;
    if (active) {
        const int pf = __popcll(wm & ((1ull << lane) - 1ull));
        sList[wave][pf] = (unsigned short)lane;
    }
    asm volatile("s_waitcnt lgkmcnt(0)" ::: "memory");
    __builtin_amdgcn_sched_barrier(0);

    // tail slots alias an INACTIVE pixel (feat row never dx-overlaid) — R13 fix
    const int safe = (count < 64) ? ((int)__ffsll((long long)(~wm)) - 1) : 0;
    int lid0 = safe, lid1 = safe, lid2 = safe, lid3 = safe;
    if (0*16 + c15 < count) lid0 = sList[wave][0*16 + c15];
    if (1*16 + c15 < count) lid1 = sList[wave][1*16 + c15];
    if (2*16 + c15 < count) lid2 = sList[wave][2*16 + c15];
    if (3*16 + c15 < count) lid3 = sList[wave][3*16 + c15];

    const int srcA = ((( g<<1     ) & 3) << 4) + c15;
    const int srcB = ((((g<<1) + 1) & 3) << 4) + c15;
    const bool hi  = (g >= 2);

    if (ntiles > 0) K1_TILE_BODY(lid0);
    if (ntiles > 1) K1_TILE_BODY(lid1);
    if (ntiles > 2) K1_TILE_BODY(lid2);
    if (ntiles > 3) K1_TILE_BODY(lid3);

    asm volatile("s_waitcnt lgkmcnt(0)" ::: "memory");
    __builtin_amdgcn_sched_barrier(0);

    // ---- epilogue ----
    const float X3 = xr[3];
    float xn3 = X3;
    if (active) {
        float dx3 = *(const float*)&feat[t][20];
        xn3 = dx3 + X3;
    }

    // WAVE-COOPERATIVE exact fp32 fallback near the alpha threshold (rare).
    {
        const bool need = active && (fabsf(xn3 - 0.1f) < 1e-3f);
        unsigned long long nm = __ballot(need);
        if (nm != 0ull) {
            const int j0 = lane*2, j1 = lane*2 + 1;
            while (nm != 0ull) {
                const int src = (int)__ffsll((long long)nm) - 1;
                nm &= nm - 1ull;
                const int off_e = __shfl(off, src, 64);
                const int gx_e = off_e & 255, gy_e = off_e >> 8;
                const bool yle = gy_e > 0, yhe = gy_e < IMH-1;
                const bool xle = gx_e > 0, xhe = gx_e < IMW-1;
                float fv = 0.f;
                if (lane < 6) {
                    fv = Xb[lane*65536 + off_e];
                } else if (lane < 12) {
                    const float* P = Xb + (lane-1)*65536 + off_e;
                    float tl = (yle&&xle) ? P[-257] : 0.f, tr = (yle&&xhe) ? P[-255] : 0.f;
                    float ml = xle ? P[-1] : 0.f,          mr = xhe ? P[1] : 0.f;
                    float bl = (yhe&&xle) ? P[255] : 0.f,  br = (yhe&&xhe) ? P[257] : 0.f;
                    fv = ((tr-tl) + 2.f*(mr-ml) + (br-bl)) * 0.125f;
                } else if (lane < 18) {
                    const float* P = Xb + (lane-2)*65536 + off_e;
                    float tl = (yle&&xle) ? P[-257] : 0.f, tc = yle ? P[-256] : 0.f, tr = (yle&&xhe) ? P[-255] : 0.f;
                    float bl = (yhe&&xle) ? P[255]  : 0.f, bc = yhe ? P[256]  : 0.f, br = (yhe&&xhe) ? P[257]  : 0.f;
                    fv = ((bl + 2.f*bc + br) - (tl + 2.f*tc + tr)) * 0.125f;
                }
                float fe[18];
                #pragma unroll
                for (int k = 0; k < 18; ++k) fe[k] = __shfl(fv, k, 64);
                const float* r0 = wpack + j0*WROW;
                const float* r1 = wpack + j1*WROW;
                float h0 = r0[0], h1 = r1[0];
                #pragma unroll
                for (int k = 0; k < 18; ++k) {
                    h0 = fmaf(r0[1+k], fe[k], h0);
                    h1 = fmaf(r1[1+k], fe[k], h1);
                }
                h0 = fmaxf(h0, 0.f); h1 = fmaxf(h1, 0.f);
                float d = fmaf(r0[22], h0, r1[22]*h1);
                #pragma unroll
                for (int o = 1; o < 64; o <<= 1) d += __shfl_xor(d, o, 64);
                if (lane == src) xn3 = __shfl(X3, src, 64) + d;
            }
        }
    }

    xn3buf[(size_t)b*65536 + off] = xn3;
    u32x4 da = *(const u32x4*)&feat[t][0];
    u32x4 db = *(const u32x4*)&feat[t][8];
    float* ob = out + (size_t)b*NC*65536 + off;
    unsigned dw[8] = { da.x, da.y, da.z, da.w, db.x, db.y, db.z, db.w };
    #pragma unroll
    for (int c = 0; c < NC; ++c) {
        unsigned short u = (c & 1) ? (unsigned short)(dw[c>>1] >> 16)
                                   : (unsigned short)(dw[c>>1] & 0xffff);
        const float xc = (c < 5) ? xr[c] : sXh[c-5][srh][sch];
        float val = (c == 3) ? xn3 : (active ? (bf2f(u) + xc) : xc);
        ob[c*65536] = val;
    }
}

// ================= K2: live mask; WRITE ZEROS ONLY where live==0 =================
// out already holds xn (from k1); live==1 pixels need no touch. Kills the RMW.
__global__ __launch_bounds__(512, 4)
void k2_mask(const float* __restrict__ X,
             const float* __restrict__ xn3buf,
             float* out) {
    __shared__ float sPre[HR][34];
    __shared__ float sPost[HR][34];

    const int t  = threadIdx.x;
    const int x0 = blockIdx.x*32, y0 = blockIdx.y*16;
    const int b  = blockIdx.z;

    const float* X3p = X + (size_t)b*NC*65536 + 3*65536;
    const float* Pp  = xn3buf + (size_t)b*65536;
    for (int e = t; e < HR*34; e += 512) {
        int row = e / 34, col = e - row*34;
        int gy = y0 + row - 1, gx = x0 + col - 1;
        bool ok = (gy >= 0 && gy < IMH && gx >= 0 && gx < IMW);
        int idx = (gy & 255)*IMW + (gx & 255);
        sPre[row][col]  = ok ? X3p[idx] : 0.f;
        sPost[row][col] = ok ? Pp[idx]  : 0.f;
    }
    __syncthreads();

    const int lx = t & 31, ly = t >> 5;
    float mpre = -1.f, mpost = -1.f;
    #pragma unroll
    for (int dy = 0; dy < 3; ++dy)
        #pragma unroll
        for (int dxx = 0; dxx < 3; ++dxx) {
            mpre  = fmaxf(mpre,  sPre[ly+dy][lx+dxx]);
            mpost = fmaxf(mpost, sPost[ly+dy][lx+dxx]);
        }
    const bool dead = !(mpre > 0.1f && mpost > 0.1f);
    if (dead) {
        const int off = (y0+ly)*IMW + (x0+lx);
        float* ob = out + (size_t)b*NC*65536 + off;
        #pragma unroll
        for (int c = 0; c < NC; ++c) ob[c*65536] = 0.f;
    }
}

// ================= fallback fused kernel (ws too small; same as R7) ===============
__global__ __launch_bounds__(512, 3)
void nca_fused(const float* __restrict__ X,
               const float* __restrict__ rand_u,
               const float* __restrict__ b1g,
               const float* __restrict__ wpack,
               const unsigned short* __restrict__ w1pb,
               const unsigned short* __restrict__ w2b,
               const float* __restrict__ w2row3,
               float* __restrict__ out) {
    __shared__ __align__(16) float sX[NC][XS][XS];
    __shared__ __align__(16) unsigned short feat[336][FSTR];
    __shared__ __align__(16) float sB1[HID];
    __shared__ __align__(16) float sW23[HID];

    const int t    = threadIdx.x;
    const int x0   = blockIdx.x * TILE;
    const int y0   = blockIdx.y * TILE;
    const int b    = blockIdx.z;
    const int lane = t & 63;
    const int c15  = lane & 15;
    const int g    = lane >> 4;
    const int wave = t >> 6;

    const float* Xb = X + (size_t)b * NC * IMH * IMW;

    if (t < HID) { sB1[t] = b1g[t]; sW23[t] = w2row3[t]; }

    if (t < NC*XS) {
        int ch = t / XS, row = t % XS;
        int gy = y0 + row - 2;
        bool yok = (gy >= 0 && gy < IMH);
        const float* src = Xb + (size_t)ch*IMH*IMW + (size_t)(yok ? gy : 0)*IMW;
        float4 z = {0.f,0.f,0.f,0.f};
        float buf[24];
        *(float4*)&buf[0]  = (yok && x0 > 0)   ? *(const float4*)(src + x0 - 4)  : z;
        *(float4*)&buf[4]  = yok               ? *(const float4*)(src + x0)      : z;
        *(float4*)&buf[8]  = yok               ? *(const float4*)(src + x0 + 4)  : z;
        *(float4*)&buf[12] = yok               ? *(const float4*)(src + x0 + 8)  : z;
        *(float4*)&buf[16] = yok               ? *(const float4*)(src + x0 + 12) : z;
        *(float4*)&buf[20] = (yok && x0 < 240) ? *(const float4*)(src + x0 + 16) : z;
        #pragma unroll
        for (int k = 0; k < 5; ++k) {
            float4 v = { buf[4*k+2], buf[4*k+3], buf[4*k+4], buf[4*k+5] };
            *(float4*)&sX[ch][row][4*k] = v;
        }
    }
    float m_reg = 0.f;
    if (t < NPIX) {
        int py = t / HR, px = t - py*HR;
        int gy = y0 + py - 1, gx = x0 + px - 1;
        if (gy >= 0 && gy < IMH && gx >= 0 && gx < IMW)
            m_reg = (rand_u[((size_t)b << 16) + (gy << 8) + gx] < 0.5f) ? 1.f : 0.f;
    }
    __syncthreads();

    if (t < NPIX) {
        const int py = t / HR, px = t - py*HR;
        const int cy = py + 1, cx = px + 1;
        float f[18];
        #pragma unroll
        for (int c = 0; c < 6; ++c) f[c] = sX[c][cy][cx];
        #pragma unroll
        for (int i = 0; i < 6; ++i) {
            const int ch = 5 + i;
            float a  = sX[ch][cy-1][cx+1] - sX[ch][cy-1][cx-1];
            float bb = sX[ch][cy  ][cx+1] - sX[ch][cy  ][cx-1];
            float cc = sX[ch][cy+1][cx+1] - sX[ch][cy+1][cx-1];
            f[6+i] = (a + 2.f*bb + cc) * 0.125f;
        }
        #pragma unroll
        for (int i = 0; i < 6; ++i) {
            const int ch = 10 + i;
            float tp = sX[ch][cy-1][cx-1] + 2.f*sX[ch][cy-1][cx] + sX[ch][cy-1][cx+1];
            float bt = sX[ch][cy+1][cx-1] + 2.f*sX[ch][cy+1][cx] + sX[ch][cy+1][cx+1];
            f[12+i] = (bt - tp) * 0.125f;
        }
        unsigned w[9];
        #pragma unroll
        for (int q = 0; q < 9; ++q) w[q] = pack2(f[2*q], f[2*q+1]);
        u32x4 v0 = { w[0], w[1], w[2], w[3] };
        u32x4 v1 = { w[4], w[5], w[6], w[7] };
        u32x4 v2 = { w[8], 0u, 0u, 0u };
        u32x4 z4 = { 0u, 0u, 0u, 0u };
        *(u32x4*)&feat[t][0]  = v0;
        *(u32x4*)&feat[t][8]  = v1;
        *(u32x4*)&feat[t][16] = v2;
        *(u32x4*)&feat[t][24] = z4;
    } else if (t < 336) {
        u32x4 z4 = { 0u, 0u, 0u, 0u };
        *(u32x4*)&feat[t][0]  = z4;
        *(u32x4*)&feat[t][8]  = z4;
        *(u32x4*)&feat[t][16] = z4;
        *(u32x4*)&feat[t][24] = z4;
    }
    __syncthreads();

    const int srcA = ((( g<<1     ) & 3) << 4) + c15;
    const int srcB = ((((g<<1) + 1) & 3) << 4) + c15;
    const bool hi  = (g >= 2);
    #pragma unroll 1
    for (int tile = wave; tile < NTILES; tile += 8) {
        const unsigned short* w1p_ = w1pb;
        const unsigned short* w2p_ = w2b;
        asm volatile("" : "+v"(w1p_), "+v"(w2p_));

        bf16x8 fb = *(const bf16x8*)&feat[tile*16 + c15][g*8];
        f32x4 dacc = { 0.f, 0.f, 0.f, 0.f };
        float part = 0.f;
        #pragma unroll
        for (int kc = 0; kc < 4; ++kc) {
            const int nt0 = 2*kc, nt1 = 2*kc + 1;
            bf16x8 a0 = *(const bf16x8*)(w1p_ + ((nt0*16 + c15)*4 + g)*8);
            bf16x8 a1 = *(const bf16x8*)(w1p_ + ((nt1*16 + c15)*4 + g)*8);
            float4 bv0 = *(const float4*)&sB1[nt0*16 + g*4];
            float4 bv1 = *(const float4*)&sB1[nt1*16 + g*4];
            f32x4 ci0 = { bv0.x, bv0.y, bv0.z, bv0.w };
            f32x4 ci1 = { bv1.x, bv1.y, bv1.z, bv1.w };
            f32x4 acc0 = __builtin_amdgcn_mfma_f32_16x16x32_bf16(a0, fb, ci0, 0, 0, 0);
            f32x4 acc1 = __builtin_amdgcn_mfma_f32_16x16x32_bf16(a1, fb, ci1, 0, 0, 0);
            float4 wv0 = *(const float4*)&sW23[nt0*16 + g*4];
            float4 wv1 = *(const float4*)&sW23[nt1*16 + g*4];
            float h00 = fmaxf(acc0[0], 0.f), h01 = fmaxf(acc0[1], 0.f);
            float h02 = fmaxf(acc0[2], 0.f), h03 = fmaxf(acc0[3], 0.f);
            float h10 = fmaxf(acc1[0], 0.f), h11 = fmaxf(acc1[1], 0.f);
            float h12 = fmaxf(acc1[2], 0.f), h13 = fmaxf(acc1[3], 0.f);
            part = fmaf(wv0.x, h00, part); part = fmaf(wv0.y, h01, part);
            part = fmaf(wv0.z, h02, part); part = fmaf(wv0.w, h03, part);
            part = fmaf(wv1.x, h10, part); part = fmaf(wv1.y, h11, part);
            part = fmaf(wv1.z, h12, part); part = fmaf(wv1.w, h13, part);
            unsigned p00 = pack2(h00, h01), p01 = pack2(h02, h03);
            unsigned p10 = pack2(h10, h11), p11 = pack2(h12, h13);
            int a0s = __shfl((int)p00, srcA, 64);
            int b0s = __shfl((int)p10, srcA, 64);
            int a1s = __shfl((int)p01, srcA, 64);
            int b1s = __shfl((int)p11, srcA, 64);
            int a2s = __shfl((int)p00, srcB, 64);
            int b2s = __shfl((int)p10, srcB, 64);
            int a3s = __shfl((int)p01, srcB, 64);
            int b3s = __shfl((int)p11, srcB, 64);
            UB bu;
            bu.u[0] = (unsigned)(hi ? b0s : a0s);
            bu.u[1] = (unsigned)(hi ? b1s : a1s);
            bu.u[2] = (unsigned)(hi ? b2s : a2s);
            bu.u[3] = (unsigned)(hi ? b3s : a3s);
            bf16x8 w2a = *(const bf16x8*)(w2p_ + c15*128 + kc*32 + g*8);
            dacc = __builtin_amdgcn_mfma_f32_16x16x32_bf16(w2a, bu.v, dacc, 0, 0, 0);
        }
        part += __shfl_xor(part, 16, 64);
        part += __shfl_xor(part, 32, 64);
        if (g == 0) *(float*)&feat[tile*16 + c15][34] = part;
        *(unsigned*)&feat[tile*16 + c15][g*4]     = pack2(dacc[0], dacc[1]);
        *(unsigned*)&feat[tile*16 + c15][g*4 + 2] = pack2(dacc[2], dacc[3]);
    }
    __syncthreads();

    if (t < NPIX) {
        const int py = t / HR, px = t - py*HR;
        const int cy = py + 1, cx = px + 1;
        float dx3 = *(const float*)&feat[t][34];
        float X3  = sX[3][cy][cx];
        float xn3 = fmaf(dx3, m_reg, X3);
        if (m_reg != 0.f && fabsf(xn3 - 0.1f) < 1e-3f) {
            float f[18];
            #pragma unroll
            for (int c = 0; c < 6; ++c) f[c] = sX[c][cy][cx];
            #pragma unroll
            for (int i = 0; i < 6; ++i) {
                const int ch = 5 + i;
                f[6+i] = ((sX[ch][cy-1][cx+1] - sX[ch][cy-1][cx-1])
                        + 2.f*(sX[ch][cy][cx+1] - sX[ch][cy][cx-1])
                        + (sX[ch][cy+1][cx+1] - sX[ch][cy+1][cx-1])) * 0.125f;
            }
            #pragma unroll
            for (int i = 0; i < 6; ++i) {
                const int ch = 10 + i;
                f[12+i] = ((sX[ch][cy+1][cx-1] + 2.f*sX[ch][cy+1][cx] + sX[ch][cy+1][cx+1])
                         - (sX[ch][cy-1][cx-1] + 2.f*sX[ch][cy-1][cx] + sX[ch][cy-1][cx+1])) * 0.125f;
            }
            float d3 = 0.f;
            for (int j = 0; j < HID; ++j) {
                const float* row = wpack + j*WROW;
                float hj = row[0];
                #pragma unroll
                for (int k = 0; k < 18; ++k) hj = fmaf(row[1+k], f[k], hj);
                hj = fmaxf(hj, 0.f);
                d3 = fmaf(row[22], hj, d3);
            }
            xn3 = X3 + d3;
        }
        *(float*)&feat[t][32] = xn3;
    }
    __syncthreads();

    if (t < NPIX) {
        const int py = t / HR, px = t - py*HR;
        if (py >= 1 && py <= TILE && px >= 1 && px <= TILE) {
            float mpre = -1.f, mpost = -1.f;
            #pragma unroll
            for (int dy = 0; dy < 3; ++dy)
                #pragma unroll
                for (int dxx = 0; dxx < 3; ++dxx) {
                    mpre  = fmaxf(mpre,  sX[3][py+dy][px+dxx]);
                    mpost = fmaxf(mpost, *(const float*)&feat[(py-1+dy)*HR + (px-1+dxx)][32]);
                }
            const float live = (mpre > 0.1f && mpost > 0.1f) ? 1.f : 0.f;
            const int gy = y0 + py - 1, gx = x0 + px - 1;
            float* ob = out + ((size_t)b*NC)*IMH*IMW + (size_t)gy*IMW + gx;
            u32x4 da = *(const u32x4*)&feat[t][0];
            u32x4 db = *(const u32x4*)&feat[t][8];
            float xn3 = *(const float*)&feat[t][32];
            unsigned dw[8] = { da.x, da.y, da.z, da.w, db.x, db.y, db.z, db.w };
            #pragma unroll
            for (int c = 0; c < NC; ++c) {
                unsigned short u = (c & 1) ? (unsigned short)(dw[c>>1] >> 16)
                                           : (unsigned short)(dw[c>>1] & 0xffff);
                float val = (c == 3) ? xn3
                                     : fmaf(bf2f(u), m_reg, sX[c][py+1][px+1]);
                ob[(size_t)c*IMH*IMW] = val * live;
            }
        }
    }
}

extern "C" void kernel_launch(void* const* d_in, const int* in_sizes, int n_in,
                              void* d_out, int out_size, void* d_ws, size_t ws_size,
                              hipStream_t stream) {
    const float* X  = (const float*)d_in[0];
    const float* w1 = (const float*)d_in[1];
    const float* b1 = (const float*)d_in[2];
    const float* w2 = (const float*)d_in[3];
    const float* ru = (const float*)d_in[4];
    float* out = (float*)d_out;

    float* wpack          = (float*)d_ws;                            // 18432 B
    unsigned short* w1pb  = (unsigned short*)((char*)d_ws + 18432);  //  8192 B
    unsigned short* w2b   = (unsigned short*)((char*)d_ws + 26624);  //  4096 B
    float* w2row3         = (float*)((char*)d_ws + 30720);           //   512 B
    float* xn3buf         = (float*)((char*)d_ws + 32768);           // 8 MB (if available)

    prep_weights<<<1, 128, 0, stream>>>(w1, b1, w2, wpack, w1pb, w2b, w2row3);

    const size_t need = 32768 + (size_t)NB*65536*4;
    if (ws_size >= need) {
        dim3 grid1(IMW/32, IMH/8, NB);
        k1_dx<<<grid1, K1T, 0, stream>>>(X, ru, b1, wpack, w1pb, w2b, w2row3, xn3buf, out);
        dim3 grid2(IMW/32, IMH/16, NB);
        k2_mask<<<grid2, 512, 0, stream>>>(X, xn3buf, out);
    } else {
        dim3 grid(IMW/TILE, IMH/TILE, NB);
        nca_fused<<<grid, 512, 0, stream>>>(X, ru, b1, wpack, w1pb, w2b, w2row3, out);
    }
}

// Round 17
// 133.759 us; speedup vs baseline: 3.8544x; 1.1449x over previous
//
#include <hip/hip_runtime.h>
#include <hip/hip_bf16.h>
#include <cstddef>

#define NC 16
#define HID 128
#define IMH 256
#define IMW 256
#define NB 32
#define TILE 16
#define HR 18
#define XS 20
#define WROW 36
#define NPIX (HR*HR)
#define NTILES 21
#define FSTR 40
#define K1T 256
#define K1FS 24

typedef __attribute__((ext_vector_type(8))) short bf16x8;
typedef __attribute__((ext_vector_type(4))) float f32x4;
typedef __attribute__((ext_vector_type(4))) unsigned u32x4;

union UB { u32x4 u; bf16x8 v; };

static __device__ __forceinline__ unsigned short f2bf(float x) {
    union { __hip_bfloat16 b; unsigned short u; } v;
    v.b = __float2bfloat16(x);
    return v.u;
}
static __device__ __forceinline__ float bf2f(unsigned short u) {
    union { __hip_bfloat16 b; unsigned short u; } v;
    v.u = u;
    return __bfloat162float(v.b);
}
static __device__ __forceinline__ unsigned pack2(float a, float b) {
    return (unsigned)f2bf(a) | ((unsigned)f2bf(b) << 16);
}

// ---------------- weight prep ----------------
// Hidden-permutation trick: storage slot j holds actual hidden sig(j) where
//   sig(j) = 32*(nt>>1) + 8*g + 4*(nt&1) + r   (nt=j>>4, g=(j>>2)&3, r=j&3).
// With w1pb/b1p/w2row3p in slot order and w2b natural, L1's accumulator regs
// ARE the L2 B-fragment (per-lane) — no cross-lane rearrange needed.
__global__ void prep_weights(const float* __restrict__ w1,
                             const float* __restrict__ b1,
                             const float* __restrict__ w2,
                             float* __restrict__ wpack,
                             unsigned short* __restrict__ w1pb,
                             unsigned short* __restrict__ w2b,
                             float* __restrict__ w2row3p,
                             float* __restrict__ b1p) {
    int j = threadIdx.x;
    if (j >= HID) return;
    const int starts[18] = {0,3,6,9,12,15,16,18,21,24,27,30,32,33,36,39,42,45};
    const int lens[18]   = {3,3,3,3,3,1,2,3,3,3,3,2,1,3,3,3,3,3};
    float* row = wpack + j * WROW;
    row[0] = b1[j];
    #pragma unroll
    for (int f = 0; f < 18; ++f) {
        float s = 0.f;
        for (int k = 0; k < lens[f]; ++k) s += w1[j*48 + starts[f] + k];
        row[1+f] = s;
    }
    #pragma unroll
    for (int c = 0; c < NC; ++c) row[19+c] = w2[c*HID + j];
    row[35] = 0.f;
    const int nt = j >> 4, g = (j >> 2) & 3, r = j & 3;
    const int sig = (nt >> 1)*32 + g*8 + (nt & 1)*4 + r;
    float wes[18];
    #pragma unroll
    for (int f = 0; f < 18; ++f) {
        float s = 0.f;
        for (int k = 0; k < lens[f]; ++k) s += w1[sig*48 + starts[f] + k];
        wes[f] = s;
    }
    #pragma unroll
    for (int g2 = 0; g2 < 4; ++g2)
        #pragma unroll
        for (int r2 = 0; r2 < 8; ++r2) {
            int k = g2*8 + r2;
            w1pb[(j*4 + g2)*8 + r2] = f2bf(k < 18 ? wes[k] : 0.f);
        }
    b1p[j]     = b1[sig];
    w2row3p[j] = w2[3*HID + sig];
    #pragma unroll
    for (int c = 0; c < NC; ++c) w2b[c*HID + j] = f2bf(w2[c*HID + j]);  // natural
}

#define K1_TILE_BODY(LID)                                                        \
    do {                                                                         \
        const int row = wave*64 + (LID);                                         \
        bf16x8 fb;                                                               \
        if (g < 3) fb = *(const bf16x8*)&feat[row][g*8];                         \
        else { UB zz; zz.u = (u32x4){0u,0u,0u,0u}; fb = zz.v; }                  \
        f32x4 dacc = { 0.f, 0.f, 0.f, 0.f };                                     \
        float part = 0.f;                                                        \
        _Pragma("unroll")                                                        \
        for (int kc = 0; kc < 4; ++kc) {                                         \
            const int nt0 = 2*kc, nt1 = 2*kc + 1;                                \
            float4 bv0 = *(const float4*)(b1p + nt0*16 + g*4);                   \
            float4 bv1 = *(const float4*)(b1p + nt1*16 + g*4);                   \
            f32x4 ci0 = { bv0.x, bv0.y, bv0.z, bv0.w };                          \
            f32x4 ci1 = { bv1.x, bv1.y, bv1.z, bv1.w };                          \
            f32x4 acc0 = __builtin_amdgcn_mfma_f32_16x16x32_bf16(w1f[nt0], fb, ci0, 0, 0, 0); \
            f32x4 acc1 = __builtin_amdgcn_mfma_f32_16x16x32_bf16(w1f[nt1], fb, ci1, 0, 0, 0); \
            float4 wv0 = *(const float4*)(w2row3p + nt0*16 + g*4);               \
            float4 wv1 = *(const float4*)(w2row3p + nt1*16 + g*4);               \
            float h00 = fmaxf(acc0[0], 0.f), h01 = fmaxf(acc0[1], 0.f);          \
            float h02 = fmaxf(acc0[2], 0.f), h03 = fmaxf(acc0[3], 0.f);          \
            float h10 = fmaxf(acc1[0], 0.f), h11 = fmaxf(acc1[1], 0.f);          \
            float h12 = fmaxf(acc1[2], 0.f), h13 = fmaxf(acc1[3], 0.f);          \
            part = fmaf(wv0.x, h00, part); part = fmaf(wv0.y, h01, part);        \
            part = fmaf(wv0.z, h02, part); part = fmaf(wv0.w, h03, part);        \
            part = fmaf(wv1.x, h10, part); part = fmaf(wv1.y, h11, part);        \
            part = fmaf(wv1.z, h12, part); part = fmaf(wv1.w, h13, part);        \
            UB bu;                                                               \
            bu.u[0] = pack2(h00, h01);                                           \
            bu.u[1] = pack2(h02, h03);                                           \
            bu.u[2] = pack2(h10, h11);                                           \
            bu.u[3] = pack2(h12, h13);                                           \
            dacc = __builtin_amdgcn_mfma_f32_16x16x32_bf16(w2fA[kc], bu.v, dacc, 0, 0, 0); \
        }                                                                        \
        part += __shfl_xor(part, 16, 64);                                        \
        part += __shfl_xor(part, 32, 64);                                        \
        if (g == 0) *(float*)&feat[row][20] = part;                              \
        *(unsigned*)&feat[row][g*4]     = pack2(dacc[0], dacc[1]);               \
        *(unsigned*)&feat[row][g*4 + 2] = pack2(dacc[2], dacc[3]);               \
    } while (0)

// ================= K1: reg+LDS staged features + compacted MFMA MLP ===============
__global__ __launch_bounds__(K1T, 5)
void k1_dx(const float* __restrict__ X,
           const float* __restrict__ rand_u,
           const float* __restrict__ b1p,
           const float* __restrict__ wpack,
           const unsigned short* __restrict__ w1pb,
           const unsigned short* __restrict__ w2b,
           const float* __restrict__ w2row3p,
           float* __restrict__ xn3buf,
           float* __restrict__ out) {
    __shared__ __align__(16) float sXh[11][10][40];              // 17600 B
    __shared__ __align__(16) unsigned short feat[K1T][K1FS];     // 12288 B
    __shared__ unsigned short sList[4][64];                      //   512 B

    const int t    = threadIdx.x;
    const int lx   = t & 31, ly = t >> 5;
    const int x0   = blockIdx.x*32;
    const int y0   = blockIdx.y*8;
    const int gx   = x0 + lx;
    const int gy   = y0 + ly;
    const int b    = blockIdx.z;
    const int lane = t & 63;
    const int c15  = lane & 15;
    const int g    = lane >> 4;
    const int wave = t >> 6;
    const int off  = gy*IMW + gx;

    const float* Xb = X + (size_t)b * NC * IMH * IMW;

    const float ruv = rand_u[(size_t)b*65536 + off];
    float xr[5];
    #pragma unroll
    for (int c = 0; c < 5; ++c) xr[c] = Xb[c*65536 + off];

    #pragma unroll
    for (int s = t; s < 1100; s += K1T) {
        const int ch = s / 100, rem = s - ch*100, r = rem / 10, j = rem - r*10;
        const int gyr = y0 + r - 1;
        const int col = x0 - 4 + 4*j;
        const float4 z = {0.f,0.f,0.f,0.f};
        const bool ok = (gyr >= 0 && gyr < IMH && col >= 0 && col <= 252);
        float4 v = ok ? *(const float4*)(Xb + (size_t)(5+ch)*65536 + (size_t)gyr*IMW + col) : z;
        *(float4*)&sXh[ch][r][4*j] = v;
    }
    __syncthreads();
    asm volatile("" ::: "memory");

    bf16x8 w1f[8];
    #pragma unroll
    for (int nt = 0; nt < 8; ++nt)
        w1f[nt] = *(const bf16x8*)(w1pb + ((nt*16 + c15)*4 + g)*8);
    bf16x8 w2fA[4];
    #pragma unroll
    for (int kc = 0; kc < 4; ++kc)
        w2fA[kc] = *(const bf16x8*)(w2b + c15*128 + kc*32 + g*8);

    const int srh = ly + 1, sch = lx + 4;
    float f[18];
    #pragma unroll
    for (int c = 0; c < 5; ++c) f[c] = xr[c];
    f[5] = sXh[0][srh][sch];
    #pragma unroll
    for (int i = 0; i < 5; ++i) {
        float a  = sXh[i][srh-1][sch+1] - sXh[i][srh-1][sch-1];
        float bb = sXh[i][srh  ][sch+1] - sXh[i][srh  ][sch-1];
        float cc = sXh[i][srh+1][sch+1] - sXh[i][srh+1][sch-1];
        f[6+i] = (a + 2.f*bb + cc) * 0.125f;
    }
    {
        float tl = sXh[5][srh-1][sch-1], tc = sXh[5][srh-1][sch], tr = sXh[5][srh-1][sch+1];
        float ml = sXh[5][srh][sch-1],                            mr = sXh[5][srh][sch+1];
        float bl = sXh[5][srh+1][sch-1], bc = sXh[5][srh+1][sch], br = sXh[5][srh+1][sch+1];
        f[11] = ((tr-tl) + 2.f*(mr-ml) + (br-bl)) * 0.125f;
        f[12] = ((bl + 2.f*bc + br) - (tl + 2.f*tc + tr)) * 0.125f;
    }
    #pragma unroll
    for (int i = 0; i < 5; ++i) {
        const int ch = 6 + i;
        float tp = sXh[ch][srh-1][sch-1] + 2.f*sXh[ch][srh-1][sch] + sXh[ch][srh-1][sch+1];
        float bt = sXh[ch][srh+1][sch-1] + 2.f*sXh[ch][srh+1][sch] + sXh[ch][srh+1][sch+1];
        f[13+i] = (bt - tp) * 0.125f;
    }

    {
        unsigned w[9];
        #pragma unroll
        for (int q = 0; q < 9; ++q) w[q] = pack2(f[2*q], f[2*q+1]);
        u32x4 v0 = { w[0], w[1], w[2], w[3] };
        u32x4 v1 = { w[4], w[5], w[6], w[7] };
        u32x4 v2 = { w[8], 0u, 0u, 0u };
        *(u32x4*)&feat[t][0]  = v0;
        *(u32x4*)&feat[t][8]  = v1;
        *(u32x4*)&feat[t][16] = v2;
    }

    const bool active = (ruv < 0.5f);
    const unsigned long long wm = __ballot(active);
    const int count = __popcll(wm);
    const int ntiles = (count + 15) >> 4;
    if (active) {
        const int pf = __popcll(wm & ((1ull << lane) - 1ull));
        sList[wave][pf] = (unsigned short)lane;
    }
    asm volatile("s_waitcnt lgkmcnt(0)" ::: "memory");
    __builtin_amdgcn_sched_barrier(0);

    const int safe = (count < 64) ? ((int)__ffsll((long long)(~wm)) - 1) : 0;
    int lid0 = safe, lid1 = safe, lid2 = safe, lid3 = safe;
    if (0*16 + c15 < count) lid0 = sList[wave][0*16 + c15];
    if (1*16 + c15 < count) lid1 = sList[wave][1*16 + c15];
    if (2*16 + c15 < count) lid2 = sList[wave][2*16 + c15];
    if (3*16 + c15 < count) lid3 = sList[wave][3*16 + c15];

    if (ntiles > 0) K1_TILE_BODY(lid0);
    if (ntiles > 1) K1_TILE_BODY(lid1);
    if (ntiles > 2) K1_TILE_BODY(lid2);
    if (ntiles > 3) K1_TILE_BODY(lid3);

    asm volatile("s_waitcnt lgkmcnt(0)" ::: "memory");
    __builtin_amdgcn_sched_barrier(0);

    const float X3 = xr[3];
    float xn3 = X3;
    if (active) {
        float dx3 = *(const float*)&feat[t][20];
        xn3 = dx3 + X3;
    }

    {
        const bool need = active && (fabsf(xn3 - 0.1f) < 1e-3f);
        unsigned long long nm = __ballot(need);
        if (nm != 0ull) {
            const int j0 = lane*2, j1 = lane*2 + 1;
            while (nm != 0ull) {
                const int src = (int)__ffsll((long long)nm) - 1;
                nm &= nm - 1ull;
                const int off_e = __shfl(off, src, 64);
                const int gx_e = off_e & 255, gy_e = off_e >> 8;
                const bool yle = gy_e > 0, yhe = gy_e < IMH-1;
                const bool xle = gx_e > 0, xhe = gx_e < IMW-1;
                float fv = 0.f;
                if (lane < 6) {
                    fv = Xb[lane*65536 + off_e];
                } else if (lane < 12) {
                    const float* P = Xb + (lane-1)*65536 + off_e;
                    float tl = (yle&&xle) ? P[-257] : 0.f, tr = (yle&&xhe) ? P[-255] : 0.f;
                    float ml = xle ? P[-1] : 0.f,          mr = xhe ? P[1] : 0.f;
                    float bl = (yhe&&xle) ? P[255] : 0.f,  br = (yhe&&xhe) ? P[257] : 0.f;
                    fv = ((tr-tl) + 2.f*(mr-ml) + (br-bl)) * 0.125f;
                } else if (lane < 18) {
                    const float* P = Xb + (lane-2)*65536 + off_e;
                    float tl = (yle&&xle) ? P[-257] : 0.f, tc = yle ? P[-256] : 0.f, tr = (yle&&xhe) ? P[-255] : 0.f;
                    float bl = (yhe&&xle) ? P[255]  : 0.f, bc = yhe ? P[256]  : 0.f, br = (yhe&&xhe) ? P[257]  : 0.f;
                    fv = ((bl + 2.f*bc + br) - (tl + 2.f*tc + tr)) * 0.125f;
                }
                float fe[18];
                #pragma unroll
                for (int k = 0; k < 18; ++k) fe[k] = __shfl(fv, k, 64);
                const float* r0 = wpack + j0*WROW;
                const float* r1 = wpack + j1*WROW;
                float h0 = r0[0], h1 = r1[0];
                #pragma unroll
                for (int k = 0; k < 18; ++k) {
                    h0 = fmaf(r0[1+k], fe[k], h0);
                    h1 = fmaf(r1[1+k], fe[k], h1);
                }
                h0 = fmaxf(h0, 0.f); h1 = fmaxf(h1, 0.f);
                float d = fmaf(r0[22], h0, r1[22]*h1);
                #pragma unroll
                for (int o = 1; o < 64; o <<= 1) d += __shfl_xor(d, o, 64);
                if (lane == src) xn3 = __shfl(X3, src, 64) + d;
            }
        }
    }

    xn3buf[(size_t)b*65536 + off] = xn3;
    u32x4 da = *(const u32x4*)&feat[t][0];
    u32x4 db = *(const u32x4*)&feat[t][8];
    float* ob = out + (size_t)b*NC*65536 + off;
    unsigned dw[8] = { da.x, da.y, da.z, da.w, db.x, db.y, db.z, db.w };
    #pragma unroll
    for (int c = 0; c < NC; ++c) {
        unsigned short u = (c & 1) ? (unsigned short)(dw[c>>1] >> 16)
                                   : (unsigned short)(dw[c>>1] & 0xffff);
        const float xc = (c < 5) ? xr[c] : sXh[c-5][srh][sch];
        float val = (c == 3) ? xn3 : (active ? (bf2f(u) + xc) : xc);
        ob[c*65536] = val;
    }
}

// ================= K2: live mask; WRITE ZEROS ONLY where live==0 =================
__global__ __launch_bounds__(512, 4)
void k2_mask(const float* __restrict__ X,
             const float* __restrict__ xn3buf,
             float* out) {
    __shared__ float sPre[HR][34];
    __shared__ float sPost[HR][34];

    const int t  = threadIdx.x;
    const int x0 = blockIdx.x*32, y0 = blockIdx.y*16;
    const int b  = blockIdx.z;

    const float* X3p = X + (size_t)b*NC*65536 + 3*65536;
    const float* Pp  = xn3buf + (size_t)b*65536;
    for (int e = t; e < HR*34; e += 512) {
        int row = e / 34, col = e - row*34;
        int gy = y0 + row - 1, gx = x0 + col - 1;
        bool ok = (gy >= 0 && gy < IMH && gx >= 0 && gx < IMW);
        int idx = (gy & 255)*IMW + (gx & 255);
        sPre[row][col]  = ok ? X3p[idx] : 0.f;
        sPost[row][col] = ok ? Pp[idx]  : 0.f;
    }
    __syncthreads();

    const int lx = t & 31, ly = t >> 5;
    float mpre = -1.f, mpost = -1.f;
    #pragma unroll
    for (int dy = 0; dy < 3; ++dy)
        #pragma unroll
        for (int dxx = 0; dxx < 3; ++dxx) {
            mpre  = fmaxf(mpre,  sPre[ly+dy][lx+dxx]);
            mpost = fmaxf(mpost, sPost[ly+dy][lx+dxx]);
        }
    const bool dead = !(mpre > 0.1f && mpost > 0.1f);
    if (dead) {
        const int off = (y0+ly)*IMW + (x0+lx);
        float* ob = out + (size_t)b*NC*65536 + off;
        #pragma unroll
        for (int c = 0; c < NC; ++c) ob[c*65536] = 0.f;
    }
}

// ================= fallback fused kernel (ws too small) — permuted scheme ========
__global__ __launch_bounds__(512, 3)
void nca_fused(const float* __restrict__ X,
               const float* __restrict__ rand_u,
               const float* __restrict__ b1p,
               const float* __restrict__ wpack,
               const unsigned short* __restrict__ w1pb,
               const unsigned short* __restrict__ w2b,
               const float* __restrict__ w2row3p,
               float* __restrict__ out) {
    __shared__ __align__(16) float sX[NC][XS][XS];
    __shared__ __align__(16) unsigned short feat[336][FSTR];
    __shared__ __align__(16) float sB1[HID];
    __shared__ __align__(16) float sW23[HID];

    const int t    = threadIdx.x;
    const int x0   = blockIdx.x * TILE;
    const int y0   = blockIdx.y * TILE;
    const int b    = blockIdx.z;
    const int lane = t & 63;
    const int c15  = lane & 15;
    const int g    = lane >> 4;
    const int wave = t >> 6;

    const float* Xb = X + (size_t)b * NC * IMH * IMW;

    if (t < HID) { sB1[t] = b1p[t]; sW23[t] = w2row3p[t]; }

    if (t < NC*XS) {
        int ch = t / XS, row = t % XS;
        int gy = y0 + row - 2;
        bool yok = (gy >= 0 && gy < IMH);
        const float* src = Xb + (size_t)ch*IMH*IMW + (size_t)(yok ? gy : 0)*IMW;
        float4 z = {0.f,0.f,0.f,0.f};
        float buf[24];
        *(float4*)&buf[0]  = (yok && x0 > 0)   ? *(const float4*)(src + x0 - 4)  : z;
        *(float4*)&buf[4]  = yok               ? *(const float4*)(src + x0)      : z;
        *(float4*)&buf[8]  = yok               ? *(const float4*)(src + x0 + 4)  : z;
        *(float4*)&buf[12] = yok               ? *(const float4*)(src + x0 + 8)  : z;
        *(float4*)&buf[16] = yok               ? *(const float4*)(src + x0 + 12) : z;
        *(float4*)&buf[20] = (yok && x0 < 240) ? *(const float4*)(src + x0 + 16) : z;
        #pragma unroll
        for (int k = 0; k < 5; ++k) {
            float4 v = { buf[4*k+2], buf[4*k+3], buf[4*k+4], buf[4*k+5] };
            *(float4*)&sX[ch][row][4*k] = v;
        }
    }
    float m_reg = 0.f;
    if (t < NPIX) {
        int py = t / HR, px = t - py*HR;
        int gy = y0 + py - 1, gx = x0 + px - 1;
        if (gy >= 0 && gy < IMH && gx >= 0 && gx < IMW)
            m_reg = (rand_u[((size_t)b << 16) + (gy << 8) + gx] < 0.5f) ? 1.f : 0.f;
    }
    __syncthreads();

    if (t < NPIX) {
        const int py = t / HR, px = t - py*HR;
        const int cy = py + 1, cx = px + 1;
        float f[18];
        #pragma unroll
        for (int c = 0; c < 6; ++c) f[c] = sX[c][cy][cx];
        #pragma unroll
        for (int i = 0; i < 6; ++i) {
            const int ch = 5 + i;
            float a  = sX[ch][cy-1][cx+1] - sX[ch][cy-1][cx-1];
            float bb = sX[ch][cy  ][cx+1] - sX[ch][cy  ][cx-1];
            float cc = sX[ch][cy+1][cx+1] - sX[ch][cy+1][cx-1];
            f[6+i] = (a + 2.f*bb + cc) * 0.125f;
        }
        #pragma unroll
        for (int i = 0; i < 6; ++i) {
            const int ch = 10 + i;
            float tp = sX[ch][cy-1][cx-1] + 2.f*sX[ch][cy-1][cx] + sX[ch][cy-1][cx+1];
            float bt = sX[ch][cy+1][cx-1] + 2.f*sX[ch][cy+1][cx] + sX[ch][cy+1][cx+1];
            f[12+i] = (bt - tp) * 0.125f;
        }
        unsigned w[9];
        #pragma unroll
        for (int q = 0; q < 9; ++q) w[q] = pack2(f[2*q], f[2*q+1]);
        u32x4 v0 = { w[0], w[1], w[2], w[3] };
        u32x4 v1 = { w[4], w[5], w[6], w[7] };
        u32x4 v2 = { w[8], 0u, 0u, 0u };
        u32x4 z4 = { 0u, 0u, 0u, 0u };
        *(u32x4*)&feat[t][0]  = v0;
        *(u32x4*)&feat[t][8]  = v1;
        *(u32x4*)&feat[t][16] = v2;
        *(u32x4*)&feat[t][24] = z4;
    } else if (t < 336) {
        u32x4 z4 = { 0u, 0u, 0u, 0u };
        *(u32x4*)&feat[t][0]  = z4;
        *(u32x4*)&feat[t][8]  = z4;
        *(u32x4*)&feat[t][16] = z4;
        *(u32x4*)&feat[t][24] = z4;
    }
    __syncthreads();

    #pragma unroll 1
    for (int tile = wave; tile < NTILES; tile += 8) {
        const unsigned short* w1p_ = w1pb;
        const unsigned short* w2p_ = w2b;
        asm volatile("" : "+v"(w1p_), "+v"(w2p_));

        bf16x8 fb = *(const bf16x8*)&feat[tile*16 + c15][g*8];
        f32x4 dacc = { 0.f, 0.f, 0.f, 0.f };
        float part = 0.f;
        #pragma unroll
        for (int kc = 0; kc < 4; ++kc) {
            const int nt0 = 2*kc, nt1 = 2*kc + 1;
            bf16x8 a0 = *(const bf16x8*)(w1p_ + ((nt0*16 + c15)*4 + g)*8);
            bf16x8 a1 = *(const bf16x8*)(w1p_ + ((nt1*16 + c15)*4 + g)*8);
            float4 bv0 = *(const float4*)&sB1[nt0*16 + g*4];
            float4 bv1 = *(const float4*)&sB1[nt1*16 + g*4];
            f32x4 ci0 = { bv0.x, bv0.y, bv0.z, bv0.w };
            f32x4 ci1 = { bv1.x, bv1.y, bv1.z, bv1.w };
            f32x4 acc0 = __builtin_amdgcn_mfma_f32_16x16x32_bf16(a0, fb, ci0, 0, 0, 0);
            f32x4 acc1 = __builtin_amdgcn_mfma_f32_16x16x32_bf16(a1, fb, ci1, 0, 0, 0);
            float4 wv0 = *(const float4*)&sW23[nt0*16 + g*4];
            float4 wv1 = *(const float4*)&sW23[nt1*16 + g*4];
            float h00 = fmaxf(acc0[0], 0.f), h01 = fmaxf(acc0[1], 0.f);
            float h02 = fmaxf(acc0[2], 0.f), h03 = fmaxf(acc0[3], 0.f);
            float h10 = fmaxf(acc1[0], 0.f), h11 = fmaxf(acc1[1], 0.f);
            float h12 = fmaxf(acc1[2], 0.f), h13 = fmaxf(acc1[3], 0.f);
            part = fmaf(wv0.x, h00, part); part = fmaf(wv0.y, h01, part);
            part = fmaf(wv0.z, h02, part); part = fmaf(wv0.w, h03, part);
            part = fmaf(wv1.x, h10, part); part = fmaf(wv1.y, h11, part);
            part = fmaf(wv1.z, h12, part); part = fmaf(wv1.w, h13, part);
            UB bu;
            bu.u[0] = pack2(h00, h01);
            bu.u[1] = pack2(h02, h03);
            bu.u[2] = pack2(h10, h11);
            bu.u[3] = pack2(h12, h13);
            bf16x8 w2a = *(const bf16x8*)(w2p_ + c15*128 + kc*32 + g*8);
            dacc = __builtin_amdgcn_mfma_f32_16x16x32_bf16(w2a, bu.v, dacc, 0, 0, 0);
        }
        part += __shfl_xor(part, 16, 64);
        part += __shfl_xor(part, 32, 64);
        if (g == 0) *(float*)&feat[tile*16 + c15][34] = part;
        *(unsigned*)&feat[tile*16 + c15][g*4]     = pack2(dacc[0], dacc[1]);
        *(unsigned*)&feat[tile*16 + c15][g*4 + 2] = pack2(dacc[2], dacc[3]);
    }
    __syncthreads();

    if (t < NPIX) {
        const int py = t / HR, px = t - py*HR;
        const int cy = py + 1, cx = px + 1;
        float dx3 = *(const float*)&feat[t][34];
        float X3  = sX[3][cy][cx];
        float xn3 = fmaf(dx3, m_reg, X3);
        if (m_reg != 0.f && fabsf(xn3 - 0.1f) < 1e-3f) {
            float f[18];
            #pragma unroll
            for (int c = 0; c < 6; ++c) f[c] = sX[c][cy][cx];
            #pragma unroll
            for (int i = 0; i < 6; ++i) {
                const int ch = 5 + i;
                f[6+i] = ((sX[ch][cy-1][cx+1] - sX[ch][cy-1][cx-1])
                        + 2.f*(sX[ch][cy][cx+1] - sX[ch][cy][cx-1])
                        + (sX[ch][cy+1][cx+1] - sX[ch][cy+1][cx-1])) * 0.125f;
            }
            #pragma unroll
            for (int i = 0; i < 6; ++i) {
                const int ch = 10 + i;
                f[12+i] = ((sX[ch][cy+1][cx-1] + 2.f*sX[ch][cy+1][cx] + sX[ch][cy+1][cx+1])
                         - (sX[ch][cy-1][cx-1] + 2.f*sX[ch][cy-1][cx] + sX[ch][cy-1][cx+1])) * 0.125f;
            }
            float d3 = 0.f;
            for (int j = 0; j < HID; ++j) {
                const float* row = wpack + j*WROW;
                float hj = row[0];
                #pragma unroll
                for (int k = 0; k < 18; ++k) hj = fmaf(row[1+k], f[k], hj);
                hj = fmaxf(hj, 0.f);
                d3 = fmaf(row[22], hj, d3);
            }
            xn3 = X3 + d3;
        }
        *(float*)&feat[t][32] = xn3;
    }
    __syncthreads();

    if (t < NPIX) {
        const int py = t / HR, px = t - py*HR;
        if (py >= 1 && py <= TILE && px >= 1 && px <= TILE) {
            float mpre = -1.f, mpost = -1.f;
            #pragma unroll
            for (int dy = 0; dy < 3; ++dy)
                #pragma unroll
                for (int dxx = 0; dxx < 3; ++dxx) {
                    mpre  = fmaxf(mpre,  sX[3][py+dy][px+dxx]);
                    mpost = fmaxf(mpost, *(const float*)&feat[(py-1+dy)*HR + (px-1+dxx)][32]);
                }
            const float live = (mpre > 0.1f && mpost > 0.1f) ? 1.f : 0.f;
            const int gy = y0 + py - 1, gx = x0 + px - 1;
            float* ob = out + ((size_t)b*NC)*IMH*IMW + (size_t)gy*IMW + gx;
            u32x4 da = *(const u32x4*)&feat[t][0];
            u32x4 db = *(const u32x4*)&feat[t][8];
            float xn3 = *(const float*)&feat[t][32];
            unsigned dw[8] = { da.x, da.y, da.z, da.w, db.x, db.y, db.z, db.w };
            #pragma unroll
            for (int c = 0; c < NC; ++c) {
                unsigned short u = (c & 1) ? (unsigned short)(dw[c>>1] >> 16)
                                           : (unsigned short)(dw[c>>1] & 0xffff);
                float val = (c == 3) ? xn3
                                     : fmaf(bf2f(u), m_reg, sX[c][py+1][px+1]);
                ob[(size_t)c*IMH*IMW] = val * live;
            }
        }
    }
}

extern "C" void kernel_launch(void* const* d_in, const int* in_sizes, int n_in,
                              void* d_out, int out_size, void* d_ws, size_t ws_size,
                              hipStream_t stream) {
    const float* X  = (const float*)d_in[0];
    const float* w1 = (const float*)d_in[1];
    const float* b1 = (const float*)d_in[2];
    const float* w2 = (const float*)d_in[3];
    const float* ru = (const float*)d_in[4];
    float* out = (float*)d_out;

    float* wpack          = (float*)d_ws;                            // 18432 B
    unsigned short* w1pb  = (unsigned short*)((char*)d_ws + 18432);  //  8192 B
    unsigned short* w2b   = (unsigned short*)((char*)d_ws + 26624);  //  4096 B
    float* w2row3p        = (float*)((char*)d_ws + 30720);           //   512 B
    float* b1p            = (float*)((char*)d_ws + 31232);           //   512 B
    float* xn3buf         = (float*)((char*)d_ws + 32768);           // 8 MB (if available)

    prep_weights<<<1, 128, 0, stream>>>(w1, b1, w2, wpack, w1pb, w2b, w2row3p, b1p);

    const size_t need = 32768 + (size_t)NB*65536*4;
    if (ws_size >= need) {
        dim3 grid1(IMW/32, IMH/8, NB);
        k1_dx<<<grid1, K1T, 0, stream>>>(X, ru, b1p, wpack, w1pb, w2b, w2row3p, xn3buf, out);
        dim3 grid2(IMW/32, IMH/16, NB);
        k2_mask<<<grid2, 512, 0, stream>>>(X, xn3buf, out);
    } else {
        dim3 grid(IMW/TILE, IMH/TILE, NB);
        nca_fused<<<grid, 512, 0, stream>>>(X, ru, b1p, wpack, w1pb, w2b, w2row3p, out);
    }
}